// Round 1
// baseline (3847.667 us; speedup 1.0000x reference)
//
#include <hip/hip_runtime.h>
#include <hip/hip_bf16.h>
#include <math.h>

// DRAW: B=512, C=1, H=W=128, RS=WS=12, L=128, HID=512, T=16
#define BATCH 512
#define HID 512
#define LAT 128
#define TSTEPS 16
#define IMG 16384      // 128*128
#define ENC_IN 800     // 2*12*12 + 512
#define GATES 2048     // 4*HID

// ---------------------------------------------------------------- init
__global__ __launch_bounds__(256) void init_canvas(float* __restrict__ canvas,
                                                   const float* __restrict__ ci) {
    int idx = blockIdx.x * 256 + threadIdx.x;          // B*IMG
    canvas[idx] = ci[idx & (IMG - 1)];
}

__global__ __launch_bounds__(256) void init_state(float* __restrict__ he, float* __restrict__ ce,
                                                  float* __restrict__ hd, float* __restrict__ cd,
                                                  const float* __restrict__ hei,
                                                  const float* __restrict__ hdi) {
    int idx = blockIdx.x * 256 + threadIdx.x;          // B*HID
    int u = idx & (HID - 1);
    he[idx] = hei[u];
    hd[idx] = hdi[u];
    ce[idx] = 0.f;
    cd[idx] = 0.f;
}

__global__ __launch_bounds__(256) void sigmoid_final(float* __restrict__ c) {
    int idx = blockIdx.x * 256 + threadIdx.x;
    c[idx] = 1.f / (1.f + expf(-c[idx]));
}

// ---------------------------------------------------------------- attention filter bank
// Per block b: res = h[b] @ Wa.T + ba (5 vals), then Fx (12x128), Fy (12x128) normalized.
__global__ __launch_bounds__(128) void attn_filters(const float* __restrict__ h,
                                                    const float* __restrict__ Wa,
                                                    const float* __restrict__ ba,
                                                    float* __restrict__ Fx,
                                                    float* __restrict__ Fy,
                                                    float* __restrict__ inten) {
    const int b = blockIdx.x, t = threadIdx.x;
    __shared__ float red[5][128];
    __shared__ float par[5];
    __shared__ float fbuf[12][132];
    __shared__ float denom[12];
    const float* hb = h + (size_t)b * HID;
#pragma unroll
    for (int j = 0; j < 5; ++j) {
        float s = 0.f;
        for (int k = t; k < HID; k += 128) s += hb[k] * Wa[j * HID + k];
        red[j][t] = s;
    }
    __syncthreads();
    if (t < 5) {
        float s = 0.f;
        for (int k = 0; k < 128; ++k) s += red[t][k];
        par[t] = s + ba[t];
    }
    __syncthreads();
    const float gx = 129.f * (par[0] + 1.f) * 0.5f;
    const float gy = 129.f * (par[1] + 1.f) * 0.5f;
    const float var = expf(par[2]);
    const float strd = 127.f * expf(par[3]) / 11.f;
    if (t == 0) inten[b] = expf(par[4]);
    const float a = (float)t;

    // ---- Fx (over width)
#pragma unroll
    for (int i = 0; i < 12; ++i) {
        float mu = gx + ((float)i + 0.5f - 6.f) * strd;
        float d = a - mu;
        fbuf[i][t] = expf(-(d * d) / (2.f * var));
    }
    __syncthreads();
    if (t < 12) {
        float s = 0.f;
        for (int k = 0; k < 128; ++k) s += fbuf[t][k];
        denom[t] = fmaxf(s, 1e-8f);
    }
    __syncthreads();
#pragma unroll
    for (int i = 0; i < 12; ++i) Fx[(size_t)b * 1536 + i * 128 + t] = fbuf[i][t] / denom[i];
    __syncthreads();

    // ---- Fy (over height)
#pragma unroll
    for (int i = 0; i < 12; ++i) {
        float mu = gy + ((float)i + 0.5f - 6.f) * strd;
        float d = a - mu;
        fbuf[i][t] = expf(-(d * d) / (2.f * var));
    }
    __syncthreads();
    if (t < 12) {
        float s = 0.f;
        for (int k = 0; k < 128; ++k) s += fbuf[t][k];
        denom[t] = fmaxf(s, 1e-8f);
    }
    __syncthreads();
#pragma unroll
    for (int i = 0; i < 12; ++i) Fy[(size_t)b * 1536 + i * 128 + t] = fbuf[i][t] / denom[i];
}

// ---------------------------------------------------------------- read glimpse + build enc_in
// glimpse = inten * [Fy@x@FxT ; Fy@(x - sigmoid(canvas))@FxT]  -> enc_in[b][0:288]
// enc_in[b][288:800] = h_dec[b]
__global__ __launch_bounds__(128) void read_glimpse(const float* __restrict__ x,
                                                    const float* __restrict__ canvas,
                                                    const float* __restrict__ Fx,
                                                    const float* __restrict__ Fy,
                                                    const float* __restrict__ inten,
                                                    const float* __restrict__ h_dec,
                                                    float* __restrict__ enc_in) {
    const int b = blockIdx.x, t = threadIdx.x;
    __shared__ float fx[12][132], fy[12][132], tm[12][132], te[12][132];
    const float* Fxb = Fx + (size_t)b * 1536;
    const float* Fyb = Fy + (size_t)b * 1536;
    for (int i = t; i < 1536; i += 128) {
        fx[i >> 7][i & 127] = Fxb[i];
        fy[i >> 7][i & 127] = Fyb[i];
    }
    __syncthreads();
    float acc[12] = {}, acce[12] = {};
    const float* xb = x + (size_t)b * IMG;
    const float* cb = canvas + (size_t)b * IMG;
    for (int hh = 0; hh < 128; ++hh) {
        float xv = xb[hh * 128 + t];
        float cv = cb[hh * 128 + t];
        float xe = xv - 1.f / (1.f + expf(-cv));
#pragma unroll
        for (int i = 0; i < 12; ++i) {
            float f = fy[i][hh];
            acc[i] += f * xv;
            acce[i] += f * xe;
        }
    }
#pragma unroll
    for (int i = 0; i < 12; ++i) {
        tm[i][t] = acc[i];
        te[i][t] = acce[i];
    }
    __syncthreads();
    const float iv = inten[b];
    float* rb = enc_in + (size_t)b * ENC_IN;
    for (int o = t; o < 288; o += 128) {
        int ch = (o >= 144) ? 1 : 0;
        int rem = o - ch * 144;
        int ii = rem / 12, jj = rem - ii * 12;
        const float* src = ch ? te[ii] : tm[ii];
        float s = 0.f;
        for (int w2 = 0; w2 < 128; ++w2) s += src[w2] * fx[jj][w2];
        rb[o] = iv * s;
    }
    const float* hb = h_dec + (size_t)b * HID;
    for (int u = t; u < HID; u += 128) rb[288 + u] = hb[u];
}

// ---------------------------------------------------------------- generic fp32 NT GEMM
// C[z][m][n] = A_z[m][:] . W_z[n][:] + bias_z[n]   (z = blockIdx.z selects source set)
// Consumers sum the z-slabs (deterministic two-source accumulation / K-split).
template <int TM, int TN>
__global__ __launch_bounds__(256) void gemm_slab(const float* __restrict__ A0,
                                                 const float* __restrict__ W0,
                                                 const float* __restrict__ bias0, int ld0, int K0,
                                                 const float* __restrict__ A1,
                                                 const float* __restrict__ W1,
                                                 const float* __restrict__ bias1, int ld1, int K1,
                                                 float* __restrict__ C, int M, int N) {
    constexpr int BM = 16 * TM, BN = 16 * TN, BK = 16;
    __shared__ float As[BK][BM + 4];
    __shared__ float Ws[BK][BN + 4];
    const int z = blockIdx.z;
    const float* A = z ? A1 : A0;
    const float* Wm = z ? W1 : W0;
    const float* bs = z ? bias1 : bias0;
    const int ld = z ? ld1 : ld0;
    const int K = z ? K1 : K0;
    const int tid = threadIdx.x;
    const int tx = tid & 15, ty = tid >> 4;
    const int bm = blockIdx.x * BM, bn = blockIdx.y * BN;
    float acc[TM][TN] = {};
    for (int k0 = 0; k0 < K; k0 += BK) {
        __syncthreads();
        for (int i = tid; i < BM * 4; i += 256) {
            int row = i >> 2, c4 = i & 3;
            const float4 v = *(const float4*)(A + (size_t)(bm + row) * ld + k0 + c4 * 4);
            As[c4 * 4 + 0][row] = v.x;
            As[c4 * 4 + 1][row] = v.y;
            As[c4 * 4 + 2][row] = v.z;
            As[c4 * 4 + 3][row] = v.w;
        }
        for (int i = tid; i < BN * 4; i += 256) {
            int row = i >> 2, c4 = i & 3;
            int wr = bn + row;
            float4 v = make_float4(0.f, 0.f, 0.f, 0.f);
            if (wr < N) v = *(const float4*)(Wm + (size_t)wr * ld + k0 + c4 * 4);
            Ws[c4 * 4 + 0][row] = v.x;
            Ws[c4 * 4 + 1][row] = v.y;
            Ws[c4 * 4 + 2][row] = v.z;
            Ws[c4 * 4 + 3][row] = v.w;
        }
        __syncthreads();
#pragma unroll
        for (int c = 0; c < BK; ++c) {
            float a[TM], w[TN];
#pragma unroll
            for (int i = 0; i < TM; ++i) a[i] = As[c][ty * TM + i];
#pragma unroll
            for (int j = 0; j < TN; ++j) w[j] = Ws[c][tx * TN + j];
#pragma unroll
            for (int i = 0; i < TM; ++i)
#pragma unroll
                for (int j = 0; j < TN; ++j) acc[i][j] += a[i] * w[j];
        }
    }
    float* Cz = C + (size_t)z * M * N;
#pragma unroll
    for (int i = 0; i < TM; ++i) {
        const int rr = bm + ty * TM + i;
#pragma unroll
        for (int j = 0; j < TN; ++j) {
            const int cc = bn + tx * TN + j;
            if (cc < N) Cz[(size_t)rr * N + cc] = acc[i][j] + (bs ? bs[cc] : 0.f);
        }
    }
}

// ---------------------------------------------------------------- LSTM pointwise (sums 2 gate slabs)
__global__ __launch_bounds__(256) void lstm_pw(const float* __restrict__ g0,
                                               const float* __restrict__ g1,
                                               float* __restrict__ h, float* __restrict__ c) {
    int idx = blockIdx.x * 256 + threadIdx.x;  // B*HID
    int b = idx >> 9, u = idx & 511;
    size_t base = (size_t)b * GATES;
    float gi = g0[base + u] + g1[base + u];
    float gf = g0[base + 512 + u] + g1[base + 512 + u];
    float gg = g0[base + 1024 + u] + g1[base + 1024 + u];
    float go = g0[base + 1536 + u] + g1[base + 1536 + u];
    float si = 1.f / (1.f + expf(-gi));
    float sf = 1.f / (1.f + expf(-gf));
    float so = 1.f / (1.f + expf(-go));
    float cn = sf * c[idx] + si * tanhf(gg);
    c[idx] = cn;
    h[idx] = so * tanhf(cn);
}

// ---------------------------------------------------------------- z = mu + exp(lv/2)*eps, emit mu/lv
__global__ __launch_bounds__(256) void z_kernel(const float* __restrict__ s,
                                                const float* __restrict__ eps_t,
                                                float* __restrict__ z, float* __restrict__ mu_out,
                                                float* __restrict__ lv_out, int t) {
    int idx = blockIdx.x * 256 + threadIdx.x;  // B*L = 65536
    int b = idx >> 7, l = idx & 127;
    int i0 = b * 256 + l;
    float mu = s[i0] + s[131072 + i0];
    float lv = s[i0 + 128] + s[131072 + i0 + 128];
    z[idx] = mu + expf(0.5f * lv) * eps_t[idx];
    size_t o = (size_t)b * (TSTEPS * LAT) + t * LAT + l;
    mu_out[o] = mu;
    lv_out[o] = lv;
}

// ---------------------------------------------------------------- canvas += FyT @ w @ Fx / inten
__global__ __launch_bounds__(128) void write_canvas(float* __restrict__ canvas,
                                                    const float* __restrict__ w0,
                                                    const float* __restrict__ w1,
                                                    const float* __restrict__ Fx,
                                                    const float* __restrict__ Fy,
                                                    const float* __restrict__ inten) {
    const int b = blockIdx.x, t = threadIdx.x;
    __shared__ float fx[12][132], fyl[12][132], wl[12][12], tl[128][13];
    const float* Fxb = Fx + (size_t)b * 1536;
    const float* Fyb = Fy + (size_t)b * 1536;
    for (int i = t; i < 1536; i += 128) {
        fx[i >> 7][i & 127] = Fxb[i];
        fyl[i >> 7][i & 127] = Fyb[i];
    }
    for (int i = t; i < 144; i += 128) wl[i / 12][i % 12] = w0[(size_t)b * 144 + i] + w1[(size_t)b * 144 + i];
    __syncthreads();
    // tmp[h][j] = sum_i Fy[i][h] * w[i][j]   (thread t = h)
    float tj[12] = {};
#pragma unroll
    for (int i = 0; i < 12; ++i) {
        float f = fyl[i][t];
#pragma unroll
        for (int j = 0; j < 12; ++j) tj[j] += f * wl[i][j];
    }
#pragma unroll
    for (int j = 0; j < 12; ++j) tl[t][j] = tj[j];
    __syncthreads();
    const float iv = inten[b];
    float* cb = canvas + (size_t)b * IMG;
    // canvas[h][c] += (sum_j tmp[h][j]*Fx[j][c]) / inten   (thread t = column c, coalesced)
    for (int hh = 0; hh < 128; ++hh) {
        float s = 0.f;
#pragma unroll
        for (int j = 0; j < 12; ++j) s += tl[hh][j] * fx[j][t];
        cb[hh * 128 + t] += s / iv;
    }
}

// ================================================================ host
extern "C" void kernel_launch(void* const* d_in, const int* in_sizes, int n_in,
                              void* d_out, int out_size, void* d_ws, size_t ws_size,
                              hipStream_t stream) {
    const float* x = (const float*)d_in[0];
    const float* eps = (const float*)d_in[1];
    // d_in[2] = glimpses (always 16, compile-time constant here)
    const float* canvas_init = (const float*)d_in[3];
    const float* h_dec_init = (const float*)d_in[4];
    const float* h_enc_init = (const float*)d_in[5];
    const float* W_ih_enc = (const float*)d_in[6];
    const float* b_ih_enc = (const float*)d_in[7];
    const float* W_hh_enc = (const float*)d_in[8];
    const float* b_hh_enc = (const float*)d_in[9];
    const float* W_ih_dec = (const float*)d_in[10];
    const float* b_ih_dec = (const float*)d_in[11];
    const float* W_hh_dec = (const float*)d_in[12];
    const float* b_hh_dec = (const float*)d_in[13];
    const float* W_samp = (const float*)d_in[14];
    const float* b_samp = (const float*)d_in[15];
    const float* W_rattn = (const float*)d_in[16];
    const float* b_rattn = (const float*)d_in[17];
    const float* W_wattn = (const float*)d_in[18];
    const float* b_wattn = (const float*)d_in[19];
    const float* W_writer = (const float*)d_in[20];
    const float* b_writer = (const float*)d_in[21];

    float* out = (float*)d_out;
    float* canvas = out;                       // B*IMG, sigmoid applied in place at end
    float* out_mu = out + (size_t)BATCH * IMG; // B*T*L
    float* out_lv = out_mu + (size_t)BATCH * TSTEPS * LAT;

    float* ws = (float*)d_ws;
    size_t off = 0;
    auto alloc = [&](size_t n) { float* p = ws + off; off += n; return p; };
    float* h_enc = alloc((size_t)BATCH * HID);
    float* c_enc = alloc((size_t)BATCH * HID);
    float* h_dec = alloc((size_t)BATCH * HID);
    float* c_dec = alloc((size_t)BATCH * HID);
    float* enc_in = alloc((size_t)BATCH * ENC_IN);
    float* gates = alloc((size_t)2 * BATCH * GATES);
    float* sbuf = alloc((size_t)2 * BATCH * 256);
    float* zbuf = alloc((size_t)BATCH * LAT);
    float* wbuf = alloc((size_t)2 * BATCH * 144);
    float* Fx_r = alloc((size_t)BATCH * 1536);
    float* Fy_r = alloc((size_t)BATCH * 1536);
    float* Fx_w = alloc((size_t)BATCH * 1536);
    float* Fy_w = alloc((size_t)BATCH * 1536);
    float* inten_r = alloc(BATCH);
    float* inten_w = alloc(BATCH);

    init_canvas<<<BATCH * IMG / 256, 256, 0, stream>>>(canvas, canvas_init);
    init_state<<<BATCH * HID / 256, 256, 0, stream>>>(h_enc, c_enc, h_dec, c_dec, h_enc_init, h_dec_init);

    for (int t = 0; t < TSTEPS; ++t) {
        attn_filters<<<BATCH, 128, 0, stream>>>(h_dec, W_rattn, b_rattn, Fx_r, Fy_r, inten_r);
        read_glimpse<<<BATCH, 128, 0, stream>>>(x, canvas, Fx_r, Fy_r, inten_r, h_dec, enc_in);
        // encoder gates: enc_in @ W_ih_enc.T  (z=0)  +  h_enc @ W_hh_enc.T  (z=1)
        gemm_slab<4, 4><<<dim3(8, 32, 2), 256, 0, stream>>>(
            enc_in, W_ih_enc, b_ih_enc, ENC_IN, ENC_IN,
            h_enc, W_hh_enc, b_hh_enc, HID, HID, gates, BATCH, GATES);
        lstm_pw<<<BATCH * HID / 256, 256, 0, stream>>>(gates, gates + (size_t)BATCH * GATES, h_enc, c_enc);
        // samp: h_enc @ W_samp.T, K-split 256|256 into 2 slabs
        gemm_slab<4, 1><<<dim3(8, 16, 2), 256, 0, stream>>>(
            h_enc, W_samp, b_samp, HID, 256,
            h_enc + 256, W_samp + 256, nullptr, HID, 256, sbuf, BATCH, 256);
        z_kernel<<<BATCH * LAT / 256, 256, 0, stream>>>(sbuf, eps + (size_t)t * BATCH * LAT, zbuf,
                                                        out_mu, out_lv, t);
        // decoder gates: z @ W_ih_dec.T (z=0) + h_dec @ W_hh_dec.T (z=1)
        gemm_slab<4, 4><<<dim3(8, 32, 2), 256, 0, stream>>>(
            zbuf, W_ih_dec, b_ih_dec, LAT, LAT,
            h_dec, W_hh_dec, b_hh_dec, HID, HID, gates, BATCH, GATES);
        lstm_pw<<<BATCH * HID / 256, 256, 0, stream>>>(gates, gates + (size_t)BATCH * GATES, h_dec, c_dec);
        // writer patch: h_dec @ W_writer.T, K-split 256|256
        gemm_slab<4, 1><<<dim3(8, 9, 2), 256, 0, stream>>>(
            h_dec, W_writer, b_writer, HID, 256,
            h_dec + 256, W_writer + 256, nullptr, HID, 256, wbuf, BATCH, 144);
        attn_filters<<<BATCH, 128, 0, stream>>>(h_dec, W_wattn, b_wattn, Fx_w, Fy_w, inten_w);
        write_canvas<<<BATCH, 128, 0, stream>>>(canvas, wbuf, wbuf + (size_t)BATCH * 144, Fx_w, Fy_w, inten_w);
    }
    sigmoid_final<<<BATCH * IMG / 256, 256, 0, stream>>>(canvas);
}

// Round 3
// 2713.748 us; speedup vs baseline: 1.4178x; 1.4178x over previous
//
#include <hip/hip_runtime.h>
#include <hip/hip_bf16.h>
#include <math.h>

// DRAW: B=512, C=1, H=W=128, RS=WS=12, L=128, HID=512, T=16
#define BATCH 512
#define HID 512
#define LAT 128
#define TSTEPS 16
#define IMG 16384      // 128*128
#define ENC_IN 800     // 2*12*12 + 512
#define GATES 2048     // 4*HID

// bf16x3 split-GEMM geometry. A and W are both stored [hi | lo] (2 sections of
// width SEC). The virtual K space is 3*SEC: v0 = A_hi*W_hi, v1 = A_hi*W_lo,
// v2 = A_lo*W_hi (lo*lo dropped, ~2^-16 relative).
#define SEC_E 1344     // enc K = 800+512 = 1312, padded to 1344 (W pad = 0)
#define SEC_D 640      // dec K = 128+512 = 640

typedef __attribute__((ext_vector_type(8))) short short8;
typedef __attribute__((ext_vector_type(4))) float f32x4;

// ---------------------------------------------------------------- helpers
__device__ __forceinline__ void gload16(const void* g, void* l) {
    __builtin_amdgcn_global_load_lds((const __attribute__((address_space(1))) unsigned int*)g,
                                     (__attribute__((address_space(3))) unsigned int*)l, 16, 0, 0);
}

__device__ __forceinline__ void bsplit(float v, unsigned short& hi, unsigned short& lo) {
    unsigned u = __float_as_uint(v);
    unsigned uh = (u + (0x7FFFu + ((u >> 16) & 1u))) & 0xFFFF0000u;   // RNE bf16
    hi = (unsigned short)(uh >> 16);
    float r = v - __uint_as_float(uh);                                 // exact residual
    unsigned ur = __float_as_uint(r);
    unsigned ul = (ur + (0x7FFFu + ((ur >> 16) & 1u))) & 0xFFFF0000u;
    lo = (unsigned short)(ul >> 16);
}

// ---------------------------------------------------------------- init
__global__ __launch_bounds__(256) void init_canvas(float* __restrict__ canvas,
                                                   const float* __restrict__ ci) {
    int idx = blockIdx.x * 256 + threadIdx.x;
    canvas[idx] = ci[idx & (IMG - 1)];
}

// also seeds the split h_enc / h_dec slices of the GEMM A-buffers
__global__ __launch_bounds__(256) void init_state(float* __restrict__ he, float* __restrict__ ce,
                                                  float* __restrict__ hd, float* __restrict__ cd,
                                                  const float* __restrict__ hei,
                                                  const float* __restrict__ hdi,
                                                  unsigned short* __restrict__ A_enc,
                                                  unsigned short* __restrict__ A_dec) {
    int idx = blockIdx.x * 256 + threadIdx.x;   // B*HID
    int b = idx >> 9, u = idx & 511;
    float ve = hei[u], vd = hdi[u];
    he[idx] = ve;
    hd[idx] = vd;
    ce[idx] = 0.f;
    cd[idx] = 0.f;
    unsigned short hi, lo;
    bsplit(ve, hi, lo);
    size_t be = (size_t)b * 2 * SEC_E;
    A_enc[be + 800 + u] = hi;
    A_enc[be + SEC_E + 800 + u] = lo;
    bsplit(vd, hi, lo);
    size_t bd = (size_t)b * 2 * SEC_D;
    A_dec[bd + 128 + u] = hi;
    A_dec[bd + SEC_D + 128 + u] = lo;
}

__global__ __launch_bounds__(256) void sigmoid_final(float* __restrict__ c) {
    int idx = blockIdx.x * 256 + threadIdx.x;
    c[idx] = 1.f / (1.f + expf(-c[idx]));
}

// ---------------------------------------------------------------- weight split prep (once/launch)
// out[n][2*SEC]: [ hi([W1|W2|0pad]) | lo(...) ].  grid: (ceil(SEC/256), N)
__global__ __launch_bounds__(256) void prep_wsplit(const float* __restrict__ W1, int K1,
                                                   const float* __restrict__ W2, int K2,
                                                   unsigned short* __restrict__ out, int SEC) {
    int kk = blockIdx.x * 256 + threadIdx.x;
    int n = blockIdx.y;
    if (kk >= SEC) return;
    float v = 0.f;
    if (kk < K1) v = W1[(size_t)n * K1 + kk];
    else if (kk < K1 + K2) v = W2[(size_t)n * K2 + (kk - K1)];
    unsigned short hi, lo;
    bsplit(v, hi, lo);
    size_t base = (size_t)n * 2 * SEC;
    out[base + kk] = hi;
    out[base + SEC + kk] = lo;
}

// ---------------------------------------------------------------- bf16x3 MFMA GEMM
// C[z][512][2048], virtual K = 3*SEC tiled by 64; per tile remap into the
// 2-section [hi|lo] storage of A (ld 2*SEC) and W (ld 2*SEC).
// 64x64 tile/block, 4 waves, BK=64, global_load_lds(16B) with pre-swizzled
// source (chunk ^= row&7), XOR-swizzled ds_read_b128, double-buffered LDS.
__global__ __launch_bounds__(256) void gemm_bf16x3(const unsigned short* __restrict__ Au,
                                                   const unsigned short* __restrict__ Wu,
                                                   float* __restrict__ C, int SEC,
                                                   int ktb0, int kte0, int ktb1, int kte1) {
    __shared__ __align__(16) char lds[2][16384];   // per buf: A [0,8192), B [8192,16384)
    const __bf16* A = (const __bf16*)Au;
    const __bf16* Wt = (const __bf16*)Wu;
    const int ld = 2 * SEC;
    const int tid = threadIdx.x;
    const int z = blockIdx.z;
    const int bm = blockIdx.x * 64;
    const int bn = blockIdx.y * 64;
    const int ktb = z ? ktb1 : ktb0;
    const int kte = z ? kte1 : kte0;

    // staging: 512 16B-chunks per matrix tile; thread i handles chunks i, i+256
    const int row0 = tid >> 3, c0 = tid & 7;
    const size_t ga0 = (size_t)(bm + row0) * ld + (size_t)((c0 ^ (row0 & 7)) * 8);
    const size_t ga1 = ga0 + (size_t)32 * ld;
    const size_t gb0 = (size_t)(bn + row0) * ld + (size_t)((c0 ^ (row0 & 7)) * 8);
    const size_t gb1 = gb0 + (size_t)32 * ld;
    const int lA0 = tid * 16, lA1 = (tid + 256) * 16;
    const int lB0 = 8192 + tid * 16, lB1 = 8192 + (tid + 256) * 16;

    // fragment ds_read byte offsets
    const int lane = tid & 63, wv = tid >> 6;
    const int rA = wv * 16 + (lane & 15);
    const int chnk = (lane >> 4) ^ (lane & 7);     // rA&7 == lane&7, rB&7 == lane&7
    const int byteA = rA * 128 + chnk * 16;
    const int byteB = 8192 + (lane & 15) * 128 + chnk * 16;

    f32x4 acc[4];
#pragma unroll
    for (int j = 0; j < 4; ++j) acc[j] = (f32x4){0.f, 0.f, 0.f, 0.f};

    auto STAGE = [&](int buf, int kt) {
        const int kw = kt * 64;
        const int ka = (kw >= SEC) ? (kw - SEC) : kw;            // A: hi,hi,lo
        const int kb = (kw >= 2 * SEC) ? (kw - 2 * SEC) : kw;    // W: hi,lo,hi
        const __bf16* a = A + ka;
        const __bf16* w = Wt + kb;
        char* l = &lds[buf][0];
        gload16(a + ga0, l + lA0);
        gload16(a + ga1, l + lA1);
        gload16(w + gb0, l + lB0);
        gload16(w + gb1, l + lB1);
    };

    STAGE(0, ktb);
    asm volatile("s_waitcnt vmcnt(0)" ::: "memory");
    __syncthreads();
    int buf = 0;
    for (int kt = ktb; kt < kte; ++kt) {
        if (kt + 1 < kte) STAGE(buf ^ 1, kt + 1);
        const char* base = &lds[buf][0];
        short8 a0 = *(const short8*)(base + byteA);
        short8 a1 = *(const short8*)(base + (byteA ^ 64));
#pragma unroll
        for (int j = 0; j < 4; ++j) {
            short8 b0 = *(const short8*)(base + (byteB + j * 2048));
            short8 b1 = *(const short8*)(base + ((byteB + j * 2048) ^ 64));
            acc[j] = __builtin_amdgcn_mfma_f32_16x16x32_bf16(a0, b0, acc[j], 0, 0, 0);
            acc[j] = __builtin_amdgcn_mfma_f32_16x16x32_bf16(a1, b1, acc[j], 0, 0, 0);
        }
        asm volatile("s_waitcnt vmcnt(0)" ::: "memory");
        __syncthreads();
        buf ^= 1;
    }
    // C/D layout: col = lane&15, row = (lane>>4)*4 + r  [m89-verified]
    float* Cz = C + (size_t)z * BATCH * GATES;
    const int crow = bm + wv * 16 + (lane >> 4) * 4;
    const int ccol = bn + (lane & 15);
#pragma unroll
    for (int j = 0; j < 4; ++j)
#pragma unroll
        for (int r = 0; r < 4; ++r)
            Cz[(size_t)(crow + r) * GATES + ccol + j * 16] = acc[j][r];
}

// ---------------------------------------------------------------- fused read:
// attn params + filter bank + glimpse; writes split glimpse|h_dec into A_enc.
__global__ __launch_bounds__(128) void read_glimpse_fused(const float* __restrict__ x,
                                                          const float* __restrict__ canvas,
                                                          const float* __restrict__ h_dec,
                                                          const float* __restrict__ Wa,
                                                          const float* __restrict__ ba,
                                                          unsigned short* __restrict__ A_enc) {
    const int b = blockIdx.x, t = threadIdx.x;
    __shared__ float red[5][128];
    __shared__ float par[5];
    __shared__ float fx[12][132], fy[12][132], tm[12][132], te[12][132];
    __shared__ float dnx[12], dny[12];
    const float* hb = h_dec + (size_t)b * HID;
#pragma unroll
    for (int j = 0; j < 5; ++j) {
        float s = 0.f;
        for (int k = t; k < HID; k += 128) s += hb[k] * Wa[j * HID + k];
        red[j][t] = s;
    }
    __syncthreads();
    if (t < 5) {
        float s = 0.f;
        for (int k = 0; k < 128; ++k) s += red[t][k];
        par[t] = s + ba[t];
    }
    __syncthreads();
    const float gx = 129.f * (par[0] + 1.f) * 0.5f;
    const float gy = 129.f * (par[1] + 1.f) * 0.5f;
    const float var = expf(par[2]);
    const float strd = 127.f * expf(par[3]) / 11.f;
    const float iv = expf(par[4]);
    const float a = (float)t;
#pragma unroll
    for (int i = 0; i < 12; ++i) {
        float off = ((float)i + 0.5f - 6.f) * strd;
        float dx = a - (gx + off), dy = a - (gy + off);
        fx[i][t] = expf(-(dx * dx) / (2.f * var));
        fy[i][t] = expf(-(dy * dy) / (2.f * var));
    }
    __syncthreads();
    if (t < 12) {
        float s = 0.f;
        for (int k = 0; k < 128; ++k) s += fx[t][k];
        dnx[t] = fmaxf(s, 1e-8f);
    } else if (t < 24) {
        float s = 0.f;
        for (int k = 0; k < 128; ++k) s += fy[t - 12][k];
        dny[t - 12] = fmaxf(s, 1e-8f);
    }
    __syncthreads();
#pragma unroll
    for (int i = 0; i < 12; ++i) {
        fx[i][t] /= dnx[i];
        fy[i][t] /= dny[i];
    }
    __syncthreads();
    // glimpse: tm = Fy@x, te = Fy@(x - sigmoid(canvas))  (thread t = column)
    float acc[12] = {}, acce[12] = {};
    const float* xb = x + (size_t)b * IMG;
    const float* cb = canvas + (size_t)b * IMG;
    for (int hh = 0; hh < 128; ++hh) {
        float xv = xb[hh * 128 + t];
        float cv = cb[hh * 128 + t];
        float xe = xv - 1.f / (1.f + expf(-cv));
#pragma unroll
        for (int i = 0; i < 12; ++i) {
            float f = fy[i][hh];
            acc[i] += f * xv;
            acce[i] += f * xe;
        }
    }
#pragma unroll
    for (int i = 0; i < 12; ++i) {
        tm[i][t] = acc[i];
        te[i][t] = acce[i];
    }
    __syncthreads();
    unsigned short hi, lo;
    unsigned short* rb = A_enc + (size_t)b * 2 * SEC_E;
    for (int o = t; o < 288; o += 128) {
        int ch = (o >= 144) ? 1 : 0;
        int rem = o - ch * 144;
        int ii = rem / 12, jj = rem - ii * 12;
        const float* src = ch ? te[ii] : tm[ii];
        float s = 0.f;
        for (int w2 = 0; w2 < 128; ++w2) s += src[w2] * fx[jj][w2];
        bsplit(iv * s, hi, lo);
        rb[o] = hi;
        rb[SEC_E + o] = lo;
    }
    for (int u = t; u < HID; u += 128) {
        bsplit(hb[u], hi, lo);
        rb[288 + u] = hi;
        rb[SEC_E + 288 + u] = lo;
    }
    if (t < 32) {       // zero the K pad (ws is re-poisoned each launch)
        rb[1312 + t] = 0;
        rb[SEC_E + 1312 + t] = 0;
    }
}

// ---------------------------------------------------------------- fp32 NT GEMM (samp/writer)
template <int TM, int TN>
__global__ __launch_bounds__(256) void gemm_slab(const float* __restrict__ A0,
                                                 const float* __restrict__ W0,
                                                 const float* __restrict__ bias0, int ld0, int K0,
                                                 const float* __restrict__ A1,
                                                 const float* __restrict__ W1,
                                                 const float* __restrict__ bias1, int ld1, int K1,
                                                 float* __restrict__ C, int M, int N) {
    constexpr int BM = 16 * TM, BN = 16 * TN, BK = 16;
    __shared__ float As[BK][BM + 4];
    __shared__ float Ws[BK][BN + 4];
    const int z = blockIdx.z;
    const float* A = z ? A1 : A0;
    const float* Wm = z ? W1 : W0;
    const float* bs = z ? bias1 : bias0;
    const int ld = z ? ld1 : ld0;
    const int K = z ? K1 : K0;
    const int tid = threadIdx.x;
    const int tx = tid & 15, ty = tid >> 4;
    const int bm = blockIdx.x * BM, bn = blockIdx.y * BN;
    float acc[TM][TN] = {};
    for (int k0 = 0; k0 < K; k0 += BK) {
        __syncthreads();
        for (int i = tid; i < BM * 4; i += 256) {
            int row = i >> 2, c4 = i & 3;
            const float4 v = *(const float4*)(A + (size_t)(bm + row) * ld + k0 + c4 * 4);
            As[c4 * 4 + 0][row] = v.x;
            As[c4 * 4 + 1][row] = v.y;
            As[c4 * 4 + 2][row] = v.z;
            As[c4 * 4 + 3][row] = v.w;
        }
        for (int i = tid; i < BN * 4; i += 256) {
            int row = i >> 2, c4 = i & 3;
            int wr = bn + row;
            float4 v = make_float4(0.f, 0.f, 0.f, 0.f);
            if (wr < N) v = *(const float4*)(Wm + (size_t)wr * ld + k0 + c4 * 4);
            Ws[c4 * 4 + 0][row] = v.x;
            Ws[c4 * 4 + 1][row] = v.y;
            Ws[c4 * 4 + 2][row] = v.z;
            Ws[c4 * 4 + 3][row] = v.w;
        }
        __syncthreads();
#pragma unroll
        for (int c = 0; c < BK; ++c) {
            float a[TM], w[TN];
#pragma unroll
            for (int i = 0; i < TM; ++i) a[i] = As[c][ty * TM + i];
#pragma unroll
            for (int j = 0; j < TN; ++j) w[j] = Ws[c][tx * TN + j];
#pragma unroll
            for (int i = 0; i < TM; ++i)
#pragma unroll
                for (int j = 0; j < TN; ++j) acc[i][j] += a[i] * w[j];
        }
    }
    float* Cz = C + (size_t)z * M * N;
#pragma unroll
    for (int i = 0; i < TM; ++i) {
        const int rr = bm + ty * TM + i;
#pragma unroll
        for (int j = 0; j < TN; ++j) {
            const int cc = bn + tx * TN + j;
            if (cc < N) Cz[(size_t)rr * N + cc] = acc[i][j] + (bs ? bs[cc] : 0.f);
        }
    }
}

// ---------------------------------------------------------------- LSTM pointwise
// sums 2 gate slabs + both biases; writes h, c and the bf16 split of h into
// A-buffer slice [soff, soff+HID) (hi) / [SEC2+soff, ...) (lo).
__global__ __launch_bounds__(256) void lstm_pw(const float* __restrict__ g0,
                                               const float* __restrict__ g1,
                                               const float* __restrict__ bih,
                                               const float* __restrict__ bhh,
                                               float* __restrict__ h, float* __restrict__ c,
                                               unsigned short* __restrict__ split_out,
                                               int soff, int SEC2) {
    int idx = blockIdx.x * 256 + threadIdx.x;  // B*HID
    int b = idx >> 9, u = idx & 511;
    size_t base = (size_t)b * GATES;
    float gi = g0[base + u] + g1[base + u] + bih[u] + bhh[u];
    float gf = g0[base + 512 + u] + g1[base + 512 + u] + bih[512 + u] + bhh[512 + u];
    float gg = g0[base + 1024 + u] + g1[base + 1024 + u] + bih[1024 + u] + bhh[1024 + u];
    float go = g0[base + 1536 + u] + g1[base + 1536 + u] + bih[1536 + u] + bhh[1536 + u];
    float si = 1.f / (1.f + expf(-gi));
    float sf = 1.f / (1.f + expf(-gf));
    float so = 1.f / (1.f + expf(-go));
    float cn = sf * c[idx] + si * tanhf(gg);
    c[idx] = cn;
    float hn = so * tanhf(cn);
    h[idx] = hn;
    unsigned short hi, lo;
    bsplit(hn, hi, lo);
    size_t sb = (size_t)b * 2 * SEC2;
    split_out[sb + soff + u] = hi;
    split_out[sb + SEC2 + soff + u] = lo;
}

// ---------------------------------------------------------------- z = mu + exp(lv/2)*eps
// writes split z into A_dec[0:128], mu/lv into outputs
__global__ __launch_bounds__(256) void z_kernel(const float* __restrict__ s,
                                                const float* __restrict__ eps_t,
                                                unsigned short* __restrict__ A_dec,
                                                float* __restrict__ mu_out,
                                                float* __restrict__ lv_out, int t) {
    int idx = blockIdx.x * 256 + threadIdx.x;  // B*L
    int b = idx >> 7, l = idx & 127;
    int i0 = b * 256 + l;
    float mu = s[i0] + s[131072 + i0];
    float lv = s[i0 + 128] + s[131072 + i0 + 128];
    float zv = mu + expf(0.5f * lv) * eps_t[idx];
    unsigned short hi, lo;
    bsplit(zv, hi, lo);
    size_t bd = (size_t)b * 2 * SEC_D;
    A_dec[bd + l] = hi;
    A_dec[bd + SEC_D + l] = lo;
    size_t o = (size_t)b * (TSTEPS * LAT) + t * LAT + l;
    mu_out[o] = mu;
    lv_out[o] = lv;
}

// ---------------------------------------------------------------- fused write:
// attn params + filter bank + canvas += FyT @ w @ Fx / inten
__global__ __launch_bounds__(128) void write_canvas_fused(float* __restrict__ canvas,
                                                          const float* __restrict__ w0,
                                                          const float* __restrict__ w1,
                                                          const float* __restrict__ h_dec,
                                                          const float* __restrict__ Wa,
                                                          const float* __restrict__ ba) {
    const int b = blockIdx.x, t = threadIdx.x;
    __shared__ float red[5][128];
    __shared__ float par[5];
    __shared__ float fx[12][132], fyl[12][132];
    __shared__ float dnx[12], dny[12];
    __shared__ float wl[12][12], tl[128][13];
    const float* hb = h_dec + (size_t)b * HID;
#pragma unroll
    for (int j = 0; j < 5; ++j) {
        float s = 0.f;
        for (int k = t; k < HID; k += 128) s += hb[k] * Wa[j * HID + k];
        red[j][t] = s;
    }
    __syncthreads();
    if (t < 5) {
        float s = 0.f;
        for (int k = 0; k < 128; ++k) s += red[t][k];
        par[t] = s + ba[t];
    }
    __syncthreads();
    const float gx = 129.f * (par[0] + 1.f) * 0.5f;
    const float gy = 129.f * (par[1] + 1.f) * 0.5f;
    const float var = expf(par[2]);
    const float strd = 127.f * expf(par[3]) / 11.f;
    const float iv = expf(par[4]);
    const float a = (float)t;
#pragma unroll
    for (int i = 0; i < 12; ++i) {
        float off = ((float)i + 0.5f - 6.f) * strd;
        float dx = a - (gx + off), dy = a - (gy + off);
        fx[i][t] = expf(-(dx * dx) / (2.f * var));
        fyl[i][t] = expf(-(dy * dy) / (2.f * var));
    }
    for (int i = t; i < 144; i += 128) wl[i / 12][i % 12] = w0[(size_t)b * 144 + i] + w1[(size_t)b * 144 + i];
    __syncthreads();
    if (t < 12) {
        float s = 0.f;
        for (int k = 0; k < 128; ++k) s += fx[t][k];
        dnx[t] = fmaxf(s, 1e-8f);
    } else if (t < 24) {
        float s = 0.f;
        for (int k = 0; k < 128; ++k) s += fyl[t - 12][k];
        dny[t - 12] = fmaxf(s, 1e-8f);
    }
    __syncthreads();
#pragma unroll
    for (int i = 0; i < 12; ++i) {
        fx[i][t] /= dnx[i];
        fyl[i][t] /= dny[i];
    }
    __syncthreads();
    // tmp[h][j] = sum_i Fy[i][h] * w[i][j]   (thread t = h)
    float tj[12] = {};
#pragma unroll
    for (int i = 0; i < 12; ++i) {
        float f = fyl[i][t];
#pragma unroll
        for (int j = 0; j < 12; ++j) tj[j] += f * wl[i][j];
    }
#pragma unroll
    for (int j = 0; j < 12; ++j) tl[t][j] = tj[j];
    __syncthreads();
    float* cb = canvas + (size_t)b * IMG;
    for (int hh = 0; hh < 128; ++hh) {
        float s = 0.f;
#pragma unroll
        for (int j = 0; j < 12; ++j) s += tl[hh][j] * fx[j][t];
        cb[hh * 128 + t] += s / iv;
    }
}

// ================================================================ host
extern "C" void kernel_launch(void* const* d_in, const int* in_sizes, int n_in,
                              void* d_out, int out_size, void* d_ws, size_t ws_size,
                              hipStream_t stream) {
    const float* x = (const float*)d_in[0];
    const float* eps = (const float*)d_in[1];
    const float* canvas_init = (const float*)d_in[3];
    const float* h_dec_init = (const float*)d_in[4];
    const float* h_enc_init = (const float*)d_in[5];
    const float* W_ih_enc = (const float*)d_in[6];
    const float* b_ih_enc = (const float*)d_in[7];
    const float* W_hh_enc = (const float*)d_in[8];
    const float* b_hh_enc = (const float*)d_in[9];
    const float* W_ih_dec = (const float*)d_in[10];
    const float* b_ih_dec = (const float*)d_in[11];
    const float* W_hh_dec = (const float*)d_in[12];
    const float* b_hh_dec = (const float*)d_in[13];
    const float* W_samp = (const float*)d_in[14];
    const float* b_samp = (const float*)d_in[15];
    const float* W_rattn = (const float*)d_in[16];
    const float* b_rattn = (const float*)d_in[17];
    const float* W_wattn = (const float*)d_in[18];
    const float* b_wattn = (const float*)d_in[19];
    const float* W_writer = (const float*)d_in[20];
    const float* b_writer = (const float*)d_in[21];

    float* out = (float*)d_out;
    float* canvas = out;
    float* out_mu = out + (size_t)BATCH * IMG;
    float* out_lv = out_mu + (size_t)BATCH * TSTEPS * LAT;

    float* ws = (float*)d_ws;
    size_t off = 0;
    auto alloc = [&](size_t n) { float* p = ws + off; off += n; return p; };
    float* h_enc = alloc((size_t)BATCH * HID);
    float* c_enc = alloc((size_t)BATCH * HID);
    float* h_dec = alloc((size_t)BATCH * HID);
    float* c_dec = alloc((size_t)BATCH * HID);
    float* gates = alloc((size_t)2 * BATCH * GATES);
    float* sbuf = alloc((size_t)2 * BATCH * 256);
    float* wbuf = alloc((size_t)2 * BATCH * 144);
    unsigned short* A_enc = (unsigned short*)alloc((size_t)BATCH * SEC_E);        // B*2*SEC_E shorts
    unsigned short* A_dec = (unsigned short*)alloc((size_t)BATCH * SEC_D);
    unsigned short* Ws_enc = (unsigned short*)alloc((size_t)GATES * SEC_E);       // N*2*SEC_E shorts
    unsigned short* Ws_dec = (unsigned short*)alloc((size_t)GATES * SEC_D);
    // total ~34.5 MB of d_ws

    init_canvas<<<BATCH * IMG / 256, 256, 0, stream>>>(canvas, canvas_init);
    init_state<<<BATCH * HID / 256, 256, 0, stream>>>(h_enc, c_enc, h_dec, c_dec,
                                                      h_enc_init, h_dec_init, A_enc, A_dec);
    prep_wsplit<<<dim3((SEC_E + 255) / 256, GATES), 256, 0, stream>>>(W_ih_enc, ENC_IN, W_hh_enc, HID, Ws_enc, SEC_E);
    prep_wsplit<<<dim3((SEC_D + 255) / 256, GATES), 256, 0, stream>>>(W_ih_dec, LAT, W_hh_dec, HID, Ws_dec, SEC_D);

    const int ktE = 3 * SEC_E / 64;   // 63
    const int ktD = 3 * SEC_D / 64;   // 30

    for (int t = 0; t < TSTEPS; ++t) {
        read_glimpse_fused<<<BATCH, 128, 0, stream>>>(x, canvas, h_dec, W_rattn, b_rattn, A_enc);
        gemm_bf16x3<<<dim3(BATCH / 64, GATES / 64, 2), 256, 0, stream>>>(
            A_enc, Ws_enc, gates, SEC_E, 0, 32, 32, ktE);
        lstm_pw<<<BATCH * HID / 256, 256, 0, stream>>>(gates, gates + (size_t)BATCH * GATES,
                                                       b_ih_enc, b_hh_enc, h_enc, c_enc,
                                                       A_enc, 800, SEC_E);
        gemm_slab<4, 1><<<dim3(8, 16, 2), 256, 0, stream>>>(
            h_enc, W_samp, b_samp, HID, 256,
            h_enc + 256, W_samp + 256, nullptr, HID, 256, sbuf, BATCH, 256);
        z_kernel<<<BATCH * LAT / 256, 256, 0, stream>>>(sbuf, eps + (size_t)t * BATCH * LAT,
                                                        A_dec, out_mu, out_lv, t);
        gemm_bf16x3<<<dim3(BATCH / 64, GATES / 64, 2), 256, 0, stream>>>(
            A_dec, Ws_dec, gates, SEC_D, 0, 15, 15, ktD);
        lstm_pw<<<BATCH * HID / 256, 256, 0, stream>>>(gates, gates + (size_t)BATCH * GATES,
                                                       b_ih_dec, b_hh_dec, h_dec, c_dec,
                                                       A_dec, 128, SEC_D);
        gemm_slab<4, 1><<<dim3(8, 9, 2), 256, 0, stream>>>(
            h_dec, W_writer, b_writer, HID, 256,
            h_dec + 256, W_writer + 256, nullptr, HID, 256, wbuf, BATCH, 144);
        write_canvas_fused<<<BATCH, 128, 0, stream>>>(canvas, wbuf, wbuf + (size_t)BATCH * 144,
                                                      h_dec, W_wattn, b_wattn);
    }
    sigmoid_final<<<BATCH * IMG / 256, 256, 0, stream>>>(canvas);
}

// Round 4
// 2080.124 us; speedup vs baseline: 1.8497x; 1.3046x over previous
//
#include <hip/hip_runtime.h>
#include <hip/hip_bf16.h>
#include <math.h>

// DRAW: B=512, C=1, H=W=128, RS=WS=12, L=128, HID=512, T=16
#define BATCH 512
#define HID 512
#define LAT 128
#define TSTEPS 16
#define IMG 16384      // 128*128
#define ENC_IN 800     // 2*12*12 + 512
#define GATES 2048     // 4*HID

// bf16x3 split-GEMM geometry. A and W are both stored [hi | lo] (2 sections of
// width SEC). The virtual K space is 3*SEC: v0 = A_hi*W_hi, v1 = A_hi*W_lo,
// v2 = A_lo*W_hi (lo*lo dropped, ~2^-16 relative).
#define SEC_E 1344     // enc K = 800+512 = 1312, padded to 1344 (W pad = 0)
#define SEC_D 640      // dec K = 128+512 = 640

typedef __attribute__((ext_vector_type(8))) short short8;
typedef __attribute__((ext_vector_type(4))) float f32x4;

// ---------------------------------------------------------------- helpers
__device__ __forceinline__ void gload16(const void* g, void* l) {
    __builtin_amdgcn_global_load_lds((const __attribute__((address_space(1))) unsigned int*)g,
                                     (__attribute__((address_space(3))) unsigned int*)l, 16, 0, 0);
}

__device__ __forceinline__ void bsplit(float v, unsigned short& hi, unsigned short& lo) {
    unsigned u = __float_as_uint(v);
    unsigned uh = (u + (0x7FFFu + ((u >> 16) & 1u))) & 0xFFFF0000u;   // RNE bf16
    hi = (unsigned short)(uh >> 16);
    float r = v - __uint_as_float(uh);                                 // exact residual
    unsigned ur = __float_as_uint(r);
    unsigned ul = (ur + (0x7FFFu + ((ur >> 16) & 1u))) & 0xFFFF0000u;
    lo = (unsigned short)(ul >> 16);
}

// ---------------------------------------------------------------- init
__global__ __launch_bounds__(256) void init_canvas(float* __restrict__ canvas,
                                                   const float* __restrict__ ci) {
    int idx = blockIdx.x * 256 + threadIdx.x;
    canvas[idx] = ci[idx & (IMG - 1)];
}

// also seeds the split h_enc / h_dec slices of the GEMM A-buffers
__global__ __launch_bounds__(256) void init_state(float* __restrict__ he, float* __restrict__ ce,
                                                  float* __restrict__ hd, float* __restrict__ cd,
                                                  const float* __restrict__ hei,
                                                  const float* __restrict__ hdi,
                                                  unsigned short* __restrict__ A_enc,
                                                  unsigned short* __restrict__ A_dec) {
    int idx = blockIdx.x * 256 + threadIdx.x;   // B*HID
    int b = idx >> 9, u = idx & 511;
    float ve = hei[u], vd = hdi[u];
    he[idx] = ve;
    hd[idx] = vd;
    ce[idx] = 0.f;
    cd[idx] = 0.f;
    unsigned short hi, lo;
    bsplit(ve, hi, lo);
    size_t be = (size_t)b * 2 * SEC_E;
    A_enc[be + 800 + u] = hi;
    A_enc[be + SEC_E + 800 + u] = lo;
    bsplit(vd, hi, lo);
    size_t bd = (size_t)b * 2 * SEC_D;
    A_dec[bd + 128 + u] = hi;
    A_dec[bd + SEC_D + 128 + u] = lo;
}

__global__ __launch_bounds__(256) void sigmoid_final(float* __restrict__ c) {
    int idx = blockIdx.x * 256 + threadIdx.x;
    c[idx] = 1.f / (1.f + expf(-c[idx]));
}

// ---------------------------------------------------------------- weight split prep (once/launch)
// out[n][2*SEC]: [ hi([W1|W2|0pad]) | lo(...) ].  grid: (ceil(SEC/256), N)
__global__ __launch_bounds__(256) void prep_wsplit(const float* __restrict__ W1, int K1,
                                                   const float* __restrict__ W2, int K2,
                                                   unsigned short* __restrict__ out, int SEC) {
    int kk = blockIdx.x * 256 + threadIdx.x;
    int n = blockIdx.y;
    if (kk >= SEC) return;
    float v = 0.f;
    if (kk < K1) v = W1[(size_t)n * K1 + kk];
    else if (kk < K1 + K2) v = W2[(size_t)n * K2 + (kk - K1)];
    unsigned short hi, lo;
    bsplit(v, hi, lo);
    size_t base = (size_t)n * 2 * SEC;
    out[base + kk] = hi;
    out[base + SEC + kk] = lo;
}

// ---------------------------------------------------------------- bf16x3 MFMA GEMM
// C[z][512][2048], virtual K = 3*SEC tiled by 64; per tile remap into the
// 2-section [hi|lo] storage of A (ld 2*SEC) and W (ld 2*SEC).
// 64x64 tile/block, 4 waves, BK=64, global_load_lds(16B) with pre-swizzled
// source (chunk ^= row&7), XOR-swizzled ds_read_b128, double-buffered LDS.
__global__ __launch_bounds__(256) void gemm_bf16x3(const unsigned short* __restrict__ Au,
                                                   const unsigned short* __restrict__ Wu,
                                                   float* __restrict__ C, int SEC,
                                                   int ktb0, int kte0, int ktb1, int kte1) {
    __shared__ __align__(16) char lds[2][16384];   // per buf: A [0,8192), B [8192,16384)
    const __bf16* A = (const __bf16*)Au;
    const __bf16* Wt = (const __bf16*)Wu;
    const int ld = 2 * SEC;
    const int tid = threadIdx.x;
    const int z = blockIdx.z;
    const int bm = blockIdx.x * 64;
    const int bn = blockIdx.y * 64;
    const int ktb = z ? ktb1 : ktb0;
    const int kte = z ? kte1 : kte0;

    // staging: 512 16B-chunks per matrix tile; thread i handles chunks i, i+256
    const int row0 = tid >> 3, c0 = tid & 7;
    const size_t ga0 = (size_t)(bm + row0) * ld + (size_t)((c0 ^ (row0 & 7)) * 8);
    const size_t ga1 = ga0 + (size_t)32 * ld;
    const size_t gb0 = (size_t)(bn + row0) * ld + (size_t)((c0 ^ (row0 & 7)) * 8);
    const size_t gb1 = gb0 + (size_t)32 * ld;
    const int lA0 = tid * 16, lA1 = (tid + 256) * 16;
    const int lB0 = 8192 + tid * 16, lB1 = 8192 + (tid + 256) * 16;

    // fragment ds_read byte offsets
    const int lane = tid & 63, wv = tid >> 6;
    const int rA = wv * 16 + (lane & 15);
    const int chnk = (lane >> 4) ^ (lane & 7);     // rA&7 == lane&7, rB&7 == lane&7
    const int byteA = rA * 128 + chnk * 16;
    const int byteB = 8192 + (lane & 15) * 128 + chnk * 16;

    f32x4 acc[4];
#pragma unroll
    for (int j = 0; j < 4; ++j) acc[j] = (f32x4){0.f, 0.f, 0.f, 0.f};

    auto STAGE = [&](int buf, int kt) {
        const int kw = kt * 64;
        const int ka = (kw >= SEC) ? (kw - SEC) : kw;            // A: hi,hi,lo
        const int kb = (kw >= 2 * SEC) ? (kw - 2 * SEC) : kw;    // W: hi,lo,hi
        const __bf16* a = A + ka;
        const __bf16* w = Wt + kb;
        char* l = &lds[buf][0];
        gload16(a + ga0, l + lA0);
        gload16(a + ga1, l + lA1);
        gload16(w + gb0, l + lB0);
        gload16(w + gb1, l + lB1);
    };

    STAGE(0, ktb);
    asm volatile("s_waitcnt vmcnt(0)" ::: "memory");
    __syncthreads();
    int buf = 0;
    for (int kt = ktb; kt < kte; ++kt) {
        if (kt + 1 < kte) STAGE(buf ^ 1, kt + 1);
        const char* base = &lds[buf][0];
        short8 a0 = *(const short8*)(base + byteA);
        short8 a1 = *(const short8*)(base + (byteA ^ 64));
#pragma unroll
        for (int j = 0; j < 4; ++j) {
            short8 b0 = *(const short8*)(base + (byteB + j * 2048));
            short8 b1 = *(const short8*)(base + ((byteB + j * 2048) ^ 64));
            acc[j] = __builtin_amdgcn_mfma_f32_16x16x32_bf16(a0, b0, acc[j], 0, 0, 0);
            acc[j] = __builtin_amdgcn_mfma_f32_16x16x32_bf16(a1, b1, acc[j], 0, 0, 0);
        }
        asm volatile("s_waitcnt vmcnt(0)" ::: "memory");
        __syncthreads();
        buf ^= 1;
    }
    // C/D layout: col = lane&15, row = (lane>>4)*4 + r  [m89-verified]
    float* Cz = C + (size_t)z * BATCH * GATES;
    const int crow = bm + wv * 16 + (lane >> 4) * 4;
    const int ccol = bn + (lane & 15);
#pragma unroll
    for (int j = 0; j < 4; ++j)
#pragma unroll
        for (int r = 0; r < 4; ++r)
            Cz[(size_t)(crow + r) * GATES + ccol + j * 16] = acc[j][r];
}

// ---------------------------------------------------------------- fused read (v2: 256 thr)
// attn params + filter bank + glimpse; writes split glimpse|h_dec into A_enc.
// Glimpse loop: 4 row-groups x 64 lanes x float2 cols; LDS partial reduce.
__global__ __launch_bounds__(256) void read_glimpse_fused(const float* __restrict__ x,
                                                          const float* __restrict__ canvas,
                                                          const float* __restrict__ h_dec,
                                                          const float* __restrict__ Wa,
                                                          const float* __restrict__ ba,
                                                          unsigned short* __restrict__ A_enc) {
    const int b = blockIdx.x, t = threadIdx.x;
    __shared__ float red[5][256];
    __shared__ float par[5];
    __shared__ float fx[12][132], fy[12][132];
    __shared__ float dnx[12], dny[12];
    __shared__ float pbuf[4][12][128];
    __shared__ float tm[12][132], te[12][132];
    const float* hb = h_dec + (size_t)b * HID;
    // ---- attn params: 5 x dot(h, Wa_row)
#pragma unroll
    for (int j = 0; j < 5; ++j)
        red[j][t] = hb[t] * Wa[j * HID + t] + hb[t + 256] * Wa[j * HID + t + 256];
    __syncthreads();
    for (int o = 128; o > 0; o >>= 1) {
        if (t < o) {
#pragma unroll
            for (int j = 0; j < 5; ++j) red[j][t] += red[j][t + o];
        }
        __syncthreads();
    }
    if (t < 5) par[t] = red[t][0] + ba[t];
    __syncthreads();
    const float gx = 129.f * (par[0] + 1.f) * 0.5f;
    const float gy = 129.f * (par[1] + 1.f) * 0.5f;
    const float var = expf(par[2]);
    const float strd = 127.f * expf(par[3]) / 11.f;
    const float iv = expf(par[4]);
    const int col = t & 127;
    const float a = (float)col;
    // ---- filters: half 0 -> fx, half 1 -> fy
    if (t < 128) {
#pragma unroll
        for (int i = 0; i < 12; ++i) {
            float d = a - (gx + ((float)i + 0.5f - 6.f) * strd);
            fx[i][col] = expf(-(d * d) / (2.f * var));
        }
    } else {
#pragma unroll
        for (int i = 0; i < 12; ++i) {
            float d = a - (gy + ((float)i + 0.5f - 6.f) * strd);
            fy[i][col] = expf(-(d * d) / (2.f * var));
        }
    }
    __syncthreads();
    if (t < 12) {
        float s = 0.f;
        for (int k = 0; k < 128; ++k) s += fx[t][k];
        dnx[t] = fmaxf(s, 1e-8f);
    } else if (t >= 128 && t < 140) {
        float s = 0.f;
        for (int k = 0; k < 128; ++k) s += fy[t - 128][k];
        dny[t - 128] = fmaxf(s, 1e-8f);
    }
    __syncthreads();
    if (t < 128) {
#pragma unroll
        for (int i = 0; i < 12; ++i) fx[i][col] /= dnx[i];
    } else {
#pragma unroll
        for (int i = 0; i < 12; ++i) fy[i][col] /= dny[i];
    }
    __syncthreads();
    // ---- glimpse: group g covers rows [32g, 32g+32), lane p covers cols {2p, 2p+1}
    const int g = t >> 6, p = t & 63, c2 = p * 2;
    float2 acc2[12] = {}, acce2[12] = {};
    const float* xb = x + (size_t)b * IMG;
    const float* cb = canvas + (size_t)b * IMG;
    for (int hh = g * 32; hh < g * 32 + 32; ++hh) {
        float2 xv = *(const float2*)(xb + hh * 128 + c2);
        float2 cv = *(const float2*)(cb + hh * 128 + c2);
        float2 xe;
        xe.x = xv.x - 1.f / (1.f + expf(-cv.x));
        xe.y = xv.y - 1.f / (1.f + expf(-cv.y));
#pragma unroll
        for (int i = 0; i < 12; ++i) {
            float f = fy[i][hh];
            acc2[i].x += f * xv.x;
            acc2[i].y += f * xv.y;
            acce2[i].x += f * xe.x;
            acce2[i].y += f * xe.y;
        }
    }
#pragma unroll
    for (int i = 0; i < 12; ++i) *(float2*)(&pbuf[g][i][c2]) = acc2[i];
    __syncthreads();
    for (int it = t; it < 1536; it += 256) {
        int ii = it >> 7, cc = it & 127;
        tm[ii][cc] = pbuf[0][ii][cc] + pbuf[1][ii][cc] + pbuf[2][ii][cc] + pbuf[3][ii][cc];
    }
    __syncthreads();
#pragma unroll
    for (int i = 0; i < 12; ++i) *(float2*)(&pbuf[g][i][c2]) = acce2[i];
    __syncthreads();
    for (int it = t; it < 1536; it += 256) {
        int ii = it >> 7, cc = it & 127;
        te[ii][cc] = pbuf[0][ii][cc] + pbuf[1][ii][cc] + pbuf[2][ii][cc] + pbuf[3][ii][cc];
    }
    __syncthreads();
    // ---- FxT products -> split into A_enc
    unsigned short hi, lo;
    unsigned short* rb = A_enc + (size_t)b * 2 * SEC_E;
    for (int o = t; o < 288; o += 256) {
        int ch = (o >= 144) ? 1 : 0;
        int rem = o - ch * 144;
        int ii = rem / 12, jj = rem - ii * 12;
        const float* src = ch ? te[ii] : tm[ii];
        float s = 0.f;
        for (int w2 = 0; w2 < 128; ++w2) s += src[w2] * fx[jj][w2];
        bsplit(iv * s, hi, lo);
        rb[o] = hi;
        rb[SEC_E + o] = lo;
    }
    for (int u = t; u < HID; u += 256) {
        bsplit(hb[u], hi, lo);
        rb[288 + u] = hi;
        rb[SEC_E + 288 + u] = lo;
    }
    if (t < 32) {       // zero the K pad (ws is re-poisoned each launch)
        rb[1312 + t] = 0;
        rb[SEC_E + 1312 + t] = 0;
    }
}

// ---------------------------------------------------------------- fp32 NT GEMM (samp/writer)
template <int TM, int TN>
__global__ __launch_bounds__(256) void gemm_slab(const float* __restrict__ A0,
                                                 const float* __restrict__ W0,
                                                 const float* __restrict__ bias0, int ld0, int K0,
                                                 const float* __restrict__ A1,
                                                 const float* __restrict__ W1,
                                                 const float* __restrict__ bias1, int ld1, int K1,
                                                 float* __restrict__ C, int M, int N) {
    constexpr int BM = 16 * TM, BN = 16 * TN, BK = 16;
    __shared__ float As[BK][BM + 4];
    __shared__ float Ws[BK][BN + 4];
    const int z = blockIdx.z;
    const float* A = z ? A1 : A0;
    const float* Wm = z ? W1 : W0;
    const float* bs = z ? bias1 : bias0;
    const int ld = z ? ld1 : ld0;
    const int K = z ? K1 : K0;
    const int tid = threadIdx.x;
    const int tx = tid & 15, ty = tid >> 4;
    const int bm = blockIdx.x * BM, bn = blockIdx.y * BN;
    float acc[TM][TN] = {};
    for (int k0 = 0; k0 < K; k0 += BK) {
        __syncthreads();
        for (int i = tid; i < BM * 4; i += 256) {
            int row = i >> 2, c4 = i & 3;
            const float4 v = *(const float4*)(A + (size_t)(bm + row) * ld + k0 + c4 * 4);
            As[c4 * 4 + 0][row] = v.x;
            As[c4 * 4 + 1][row] = v.y;
            As[c4 * 4 + 2][row] = v.z;
            As[c4 * 4 + 3][row] = v.w;
        }
        for (int i = tid; i < BN * 4; i += 256) {
            int row = i >> 2, c4 = i & 3;
            int wr = bn + row;
            float4 v = make_float4(0.f, 0.f, 0.f, 0.f);
            if (wr < N) v = *(const float4*)(Wm + (size_t)wr * ld + k0 + c4 * 4);
            Ws[c4 * 4 + 0][row] = v.x;
            Ws[c4 * 4 + 1][row] = v.y;
            Ws[c4 * 4 + 2][row] = v.z;
            Ws[c4 * 4 + 3][row] = v.w;
        }
        __syncthreads();
#pragma unroll
        for (int c = 0; c < BK; ++c) {
            float a[TM], w[TN];
#pragma unroll
            for (int i = 0; i < TM; ++i) a[i] = As[c][ty * TM + i];
#pragma unroll
            for (int j = 0; j < TN; ++j) w[j] = Ws[c][tx * TN + j];
#pragma unroll
            for (int i = 0; i < TM; ++i)
#pragma unroll
                for (int j = 0; j < TN; ++j) acc[i][j] += a[i] * w[j];
        }
    }
    float* Cz = C + (size_t)z * M * N;
#pragma unroll
    for (int i = 0; i < TM; ++i) {
        const int rr = bm + ty * TM + i;
#pragma unroll
        for (int j = 0; j < TN; ++j) {
            const int cc = bn + tx * TN + j;
            if (cc < N) Cz[(size_t)rr * N + cc] = acc[i][j] + (bs ? bs[cc] : 0.f);
        }
    }
}

// ---------------------------------------------------------------- LSTM pointwise
// sums 2 gate slabs + both biases; writes h, c and the bf16 split of h into
// A-buffer slice [soff, soff+HID) (hi) / [SEC2+soff, ...) (lo).
__global__ __launch_bounds__(256) void lstm_pw(const float* __restrict__ g0,
                                               const float* __restrict__ g1,
                                               const float* __restrict__ bih,
                                               const float* __restrict__ bhh,
                                               float* __restrict__ h, float* __restrict__ c,
                                               unsigned short* __restrict__ split_out,
                                               int soff, int SEC2) {
    int idx = blockIdx.x * 256 + threadIdx.x;  // B*HID
    int b = idx >> 9, u = idx & 511;
    size_t base = (size_t)b * GATES;
    float gi = g0[base + u] + g1[base + u] + bih[u] + bhh[u];
    float gf = g0[base + 512 + u] + g1[base + 512 + u] + bih[512 + u] + bhh[512 + u];
    float gg = g0[base + 1024 + u] + g1[base + 1024 + u] + bih[1024 + u] + bhh[1024 + u];
    float go = g0[base + 1536 + u] + g1[base + 1536 + u] + bih[1536 + u] + bhh[1536 + u];
    float si = 1.f / (1.f + expf(-gi));
    float sf = 1.f / (1.f + expf(-gf));
    float so = 1.f / (1.f + expf(-go));
    float cn = sf * c[idx] + si * tanhf(gg);
    c[idx] = cn;
    float hn = so * tanhf(cn);
    h[idx] = hn;
    unsigned short hi, lo;
    bsplit(hn, hi, lo);
    size_t sb = (size_t)b * 2 * SEC2;
    split_out[sb + soff + u] = hi;
    split_out[sb + SEC2 + soff + u] = lo;
}

// ---------------------------------------------------------------- z = mu + exp(lv/2)*eps
// writes split z into A_dec[0:128], mu/lv into outputs
__global__ __launch_bounds__(256) void z_kernel(const float* __restrict__ s,
                                                const float* __restrict__ eps_t,
                                                unsigned short* __restrict__ A_dec,
                                                float* __restrict__ mu_out,
                                                float* __restrict__ lv_out, int t) {
    int idx = blockIdx.x * 256 + threadIdx.x;  // B*L
    int b = idx >> 7, l = idx & 127;
    int i0 = b * 256 + l;
    float mu = s[i0] + s[131072 + i0];
    float lv = s[i0 + 128] + s[131072 + i0 + 128];
    float zv = mu + expf(0.5f * lv) * eps_t[idx];
    unsigned short hi, lo;
    bsplit(zv, hi, lo);
    size_t bd = (size_t)b * 2 * SEC_D;
    A_dec[bd + l] = hi;
    A_dec[bd + SEC_D + l] = lo;
    size_t o = (size_t)b * (TSTEPS * LAT) + t * LAT + l;
    mu_out[o] = mu;
    lv_out[o] = lv;
}

// ---------------------------------------------------------------- fused write (v2: 256 thr)
// attn params + filter bank + canvas += FyT @ w @ Fx / inten
__global__ __launch_bounds__(256) void write_canvas_fused(float* __restrict__ canvas,
                                                          const float* __restrict__ w0,
                                                          const float* __restrict__ w1,
                                                          const float* __restrict__ h_dec,
                                                          const float* __restrict__ Wa,
                                                          const float* __restrict__ ba) {
    const int b = blockIdx.x, t = threadIdx.x;
    __shared__ float red[5][256];
    __shared__ float par[5];
    __shared__ float fx[12][132], fyl[12][132];
    __shared__ float dnx[12], dny[12];
    __shared__ float wl[12][12], tl[128][13];
    const float* hb = h_dec + (size_t)b * HID;
#pragma unroll
    for (int j = 0; j < 5; ++j)
        red[j][t] = hb[t] * Wa[j * HID + t] + hb[t + 256] * Wa[j * HID + t + 256];
    __syncthreads();
    for (int o = 128; o > 0; o >>= 1) {
        if (t < o) {
#pragma unroll
            for (int j = 0; j < 5; ++j) red[j][t] += red[j][t + o];
        }
        __syncthreads();
    }
    if (t < 5) par[t] = red[t][0] + ba[t];
    __syncthreads();
    const float gx = 129.f * (par[0] + 1.f) * 0.5f;
    const float gy = 129.f * (par[1] + 1.f) * 0.5f;
    const float var = expf(par[2]);
    const float strd = 127.f * expf(par[3]) / 11.f;
    const float riv = 1.f / expf(par[4]);
    const int col = t & 127;
    const float a = (float)col;
    if (t < 128) {
#pragma unroll
        for (int i = 0; i < 12; ++i) {
            float d = a - (gx + ((float)i + 0.5f - 6.f) * strd);
            fx[i][col] = expf(-(d * d) / (2.f * var));
        }
    } else {
#pragma unroll
        for (int i = 0; i < 12; ++i) {
            float d = a - (gy + ((float)i + 0.5f - 6.f) * strd);
            fyl[i][col] = expf(-(d * d) / (2.f * var));
        }
    }
    for (int i = t; i < 144; i += 256) wl[i / 12][i % 12] = w0[(size_t)b * 144 + i] + w1[(size_t)b * 144 + i];
    __syncthreads();
    if (t < 12) {
        float s = 0.f;
        for (int k = 0; k < 128; ++k) s += fx[t][k];
        dnx[t] = fmaxf(s, 1e-8f);
    } else if (t >= 128 && t < 140) {
        float s = 0.f;
        for (int k = 0; k < 128; ++k) s += fyl[t - 128][k];
        dny[t - 128] = fmaxf(s, 1e-8f);
    }
    __syncthreads();
    if (t < 128) {
#pragma unroll
        for (int i = 0; i < 12; ++i) fx[i][col] /= dnx[i];
    } else {
#pragma unroll
        for (int i = 0; i < 12; ++i) fyl[i][col] /= dny[i];
    }
    __syncthreads();
    // tmp[h][j] = sum_i Fy[i][h] * w[i][j]   (threads 0..127, h = t)
    if (t < 128) {
        float tj[12] = {};
#pragma unroll
        for (int i = 0; i < 12; ++i) {
            float f = fyl[i][t];
#pragma unroll
            for (int j = 0; j < 12; ++j) tj[j] += f * wl[i][j];
        }
#pragma unroll
        for (int j = 0; j < 12; ++j) tl[t][j] = tj[j];
    }
    __syncthreads();
    // canvas RMW: group g rows [32g, 32g+32), lane p cols {2p, 2p+1}
    const int g = t >> 6, p = t & 63, c2 = p * 2;
    float* cb = canvas + (size_t)b * IMG;
    for (int hh = g * 32; hh < g * 32 + 32; ++hh) {
        float sx = 0.f, sy = 0.f;
#pragma unroll
        for (int j = 0; j < 12; ++j) {
            float tv = tl[hh][j];
            sx += tv * fx[j][c2];
            sy += tv * fx[j][c2 + 1];
        }
        float2 cv = *(float2*)(cb + hh * 128 + c2);
        cv.x += sx * riv;
        cv.y += sy * riv;
        *(float2*)(cb + hh * 128 + c2) = cv;
    }
}

// ================================================================ host
extern "C" void kernel_launch(void* const* d_in, const int* in_sizes, int n_in,
                              void* d_out, int out_size, void* d_ws, size_t ws_size,
                              hipStream_t stream) {
    const float* x = (const float*)d_in[0];
    const float* eps = (const float*)d_in[1];
    const float* canvas_init = (const float*)d_in[3];
    const float* h_dec_init = (const float*)d_in[4];
    const float* h_enc_init = (const float*)d_in[5];
    const float* W_ih_enc = (const float*)d_in[6];
    const float* b_ih_enc = (const float*)d_in[7];
    const float* W_hh_enc = (const float*)d_in[8];
    const float* b_hh_enc = (const float*)d_in[9];
    const float* W_ih_dec = (const float*)d_in[10];
    const float* b_ih_dec = (const float*)d_in[11];
    const float* W_hh_dec = (const float*)d_in[12];
    const float* b_hh_dec = (const float*)d_in[13];
    const float* W_samp = (const float*)d_in[14];
    const float* b_samp = (const float*)d_in[15];
    const float* W_rattn = (const float*)d_in[16];
    const float* b_rattn = (const float*)d_in[17];
    const float* W_wattn = (const float*)d_in[18];
    const float* b_wattn = (const float*)d_in[19];
    const float* W_writer = (const float*)d_in[20];
    const float* b_writer = (const float*)d_in[21];

    float* out = (float*)d_out;
    float* canvas = out;
    float* out_mu = out + (size_t)BATCH * IMG;
    float* out_lv = out_mu + (size_t)BATCH * TSTEPS * LAT;

    float* ws = (float*)d_ws;
    size_t off = 0;
    auto alloc = [&](size_t n) { float* p = ws + off; off += n; return p; };
    float* h_enc = alloc((size_t)BATCH * HID);
    float* c_enc = alloc((size_t)BATCH * HID);
    float* h_dec = alloc((size_t)BATCH * HID);
    float* c_dec = alloc((size_t)BATCH * HID);
    float* gates = alloc((size_t)2 * BATCH * GATES);
    float* sbuf = alloc((size_t)2 * BATCH * 256);
    float* wbuf = alloc((size_t)2 * BATCH * 144);
    unsigned short* A_enc = (unsigned short*)alloc((size_t)BATCH * SEC_E);        // B*2*SEC_E shorts
    unsigned short* A_dec = (unsigned short*)alloc((size_t)BATCH * SEC_D);
    unsigned short* Ws_enc = (unsigned short*)alloc((size_t)GATES * SEC_E);       // N*2*SEC_E shorts
    unsigned short* Ws_dec = (unsigned short*)alloc((size_t)GATES * SEC_D);
    // total ~34.5 MB of d_ws

    init_canvas<<<BATCH * IMG / 256, 256, 0, stream>>>(canvas, canvas_init);
    init_state<<<BATCH * HID / 256, 256, 0, stream>>>(h_enc, c_enc, h_dec, c_dec,
                                                      h_enc_init, h_dec_init, A_enc, A_dec);
    prep_wsplit<<<dim3((SEC_E + 255) / 256, GATES), 256, 0, stream>>>(W_ih_enc, ENC_IN, W_hh_enc, HID, Ws_enc, SEC_E);
    prep_wsplit<<<dim3((SEC_D + 255) / 256, GATES), 256, 0, stream>>>(W_ih_dec, LAT, W_hh_dec, HID, Ws_dec, SEC_D);

    const int ktE = 3 * SEC_E / 64;   // 63
    const int ktD = 3 * SEC_D / 64;   // 30

    for (int t = 0; t < TSTEPS; ++t) {
        read_glimpse_fused<<<BATCH, 256, 0, stream>>>(x, canvas, h_dec, W_rattn, b_rattn, A_enc);
        gemm_bf16x3<<<dim3(BATCH / 64, GATES / 64, 2), 256, 0, stream>>>(
            A_enc, Ws_enc, gates, SEC_E, 0, 32, 32, ktE);
        lstm_pw<<<BATCH * HID / 256, 256, 0, stream>>>(gates, gates + (size_t)BATCH * GATES,
                                                       b_ih_enc, b_hh_enc, h_enc, c_enc,
                                                       A_enc, 800, SEC_E);
        gemm_slab<4, 1><<<dim3(8, 16, 2), 256, 0, stream>>>(
            h_enc, W_samp, b_samp, HID, 256,
            h_enc + 256, W_samp + 256, nullptr, HID, 256, sbuf, BATCH, 256);
        z_kernel<<<BATCH * LAT / 256, 256, 0, stream>>>(sbuf, eps + (size_t)t * BATCH * LAT,
                                                        A_dec, out_mu, out_lv, t);
        gemm_bf16x3<<<dim3(BATCH / 64, GATES / 64, 2), 256, 0, stream>>>(
            A_dec, Ws_dec, gates, SEC_D, 0, 15, 15, ktD);
        lstm_pw<<<BATCH * HID / 256, 256, 0, stream>>>(gates, gates + (size_t)BATCH * GATES,
                                                       b_ih_dec, b_hh_dec, h_dec, c_dec,
                                                       A_dec, 128, SEC_D);
        gemm_slab<4, 1><<<dim3(8, 9, 2), 256, 0, stream>>>(
            h_dec, W_writer, b_writer, HID, 256,
            h_dec + 256, W_writer + 256, nullptr, HID, 256, wbuf, BATCH, 144);
        write_canvas_fused<<<BATCH, 256, 0, stream>>>(canvas, wbuf, wbuf + (size_t)BATCH * 144,
                                                      h_dec, W_wattn, b_wattn);
    }
    sigmoid_final<<<BATCH * IMG / 256, 256, 0, stream>>>(canvas);
}

// Round 5
// 1962.254 us; speedup vs baseline: 1.9608x; 1.0601x over previous
//
#include <hip/hip_runtime.h>
#include <hip/hip_bf16.h>
#include <math.h>

// DRAW: B=512, C=1, H=W=128, RS=WS=12, L=128, HID=512, T=16
#define BATCH 512
#define HID 512
#define LAT 128
#define TSTEPS 16
#define IMG 16384      // 128*128
#define ENC_IN 800     // 2*12*12 + 512
#define GATES 2048     // 4*HID

// bf16x3 split-GEMM geometry. A and W are both stored [hi | lo] (2 sections of
// width SEC). The virtual K space is 3*SEC: v0 = A_hi*W_hi, v1 = A_hi*W_lo,
// v2 = A_lo*W_hi (lo*lo dropped, ~2^-16 relative).
// A_enc row: [glimpse 288 | h_dec 512 | h_enc 512 | pad 32] = 1344
// A_dec row: [z 128 | h_dec 512] = 640
#define SEC_E 1344
#define SEC_D 640

typedef __attribute__((ext_vector_type(8))) short short8;
typedef __attribute__((ext_vector_type(4))) float f32x4;

// ---------------------------------------------------------------- helpers
__device__ __forceinline__ void gload16(const void* g, void* l) {
    __builtin_amdgcn_global_load_lds((const __attribute__((address_space(1))) unsigned int*)g,
                                     (__attribute__((address_space(3))) unsigned int*)l, 16, 0, 0);
}

__device__ __forceinline__ void bsplit(float v, unsigned short& hi, unsigned short& lo) {
    unsigned u = __float_as_uint(v);
    unsigned uh = (u + (0x7FFFu + ((u >> 16) & 1u))) & 0xFFFF0000u;   // RNE bf16
    hi = (unsigned short)(uh >> 16);
    float r = v - __uint_as_float(uh);                                 // exact residual
    unsigned ur = __float_as_uint(r);
    unsigned ul = (ur + (0x7FFFu + ((ur >> 16) & 1u))) & 0xFFFF0000u;
    lo = (unsigned short)(ul >> 16);
}

// ---------------------------------------------------------------- init
__global__ __launch_bounds__(256) void init_canvas(float* __restrict__ canvas,
                                                   const float* __restrict__ ci) {
    int idx = blockIdx.x * 256 + threadIdx.x;
    canvas[idx] = ci[idx & (IMG - 1)];
}

// also seeds the split h_enc / h_dec slices of the GEMM A-buffers
__global__ __launch_bounds__(256) void init_state(float* __restrict__ he, float* __restrict__ ce,
                                                  float* __restrict__ hd, float* __restrict__ cd,
                                                  const float* __restrict__ hei,
                                                  const float* __restrict__ hdi,
                                                  unsigned short* __restrict__ A_enc,
                                                  unsigned short* __restrict__ A_dec) {
    int idx = blockIdx.x * 256 + threadIdx.x;   // B*HID
    int b = idx >> 9, u = idx & 511;
    float ve = hei[u], vd = hdi[u];
    he[idx] = ve;
    hd[idx] = vd;
    ce[idx] = 0.f;
    cd[idx] = 0.f;
    unsigned short hi, lo;
    bsplit(ve, hi, lo);
    size_t be = (size_t)b * 2 * SEC_E;
    A_enc[be + 800 + u] = hi;
    A_enc[be + SEC_E + 800 + u] = lo;
    bsplit(vd, hi, lo);
    size_t bd = (size_t)b * 2 * SEC_D;
    A_dec[bd + 128 + u] = hi;
    A_dec[bd + SEC_D + 128 + u] = lo;
}

__global__ __launch_bounds__(256) void sigmoid_final(float* __restrict__ c) {
    int idx = blockIdx.x * 256 + threadIdx.x;
    c[idx] = 1.f / (1.f + expf(-c[idx]));
}

// ---------------------------------------------------------------- weight split prep (once/launch)
// out[n][2*SEC]: [ hi([W1|W2|0pad]) | lo(...) ].  grid: (ceil(SEC/256), N)
__global__ __launch_bounds__(256) void prep_wsplit(const float* __restrict__ W1, int K1,
                                                   const float* __restrict__ W2, int K2,
                                                   unsigned short* __restrict__ out, int SEC) {
    int kk = blockIdx.x * 256 + threadIdx.x;
    int n = blockIdx.y;
    if (kk >= SEC) return;
    float v = 0.f;
    if (kk < K1) v = W1[(size_t)n * K1 + kk];
    else if (kk < K1 + K2) v = W2[(size_t)n * K2 + (kk - K1)];
    unsigned short hi, lo;
    bsplit(v, hi, lo);
    size_t base = (size_t)n * 2 * SEC;
    out[base + kk] = hi;
    out[base + SEC + kk] = lo;
}

// ---------------------------------------------------------------- bf16x3 MFMA GEMM
// C[z][512][2048], virtual K = 3*SEC tiled by 64; per tile remap into the
// 2-section [hi|lo] storage of A (ld 2*SEC) and W (ld 2*SEC).
__global__ __launch_bounds__(256) void gemm_bf16x3(const unsigned short* __restrict__ Au,
                                                   const unsigned short* __restrict__ Wu,
                                                   float* __restrict__ C, int SEC,
                                                   int ktb0, int kte0, int ktb1, int kte1) {
    __shared__ __align__(16) char lds[2][16384];   // per buf: A [0,8192), B [8192,16384)
    const __bf16* A = (const __bf16*)Au;
    const __bf16* Wt = (const __bf16*)Wu;
    const int ld = 2 * SEC;
    const int tid = threadIdx.x;
    const int z = blockIdx.z;
    const int bm = blockIdx.x * 64;
    const int bn = blockIdx.y * 64;
    const int ktb = z ? ktb1 : ktb0;
    const int kte = z ? kte1 : kte0;

    const int row0 = tid >> 3, c0 = tid & 7;
    const size_t ga0 = (size_t)(bm + row0) * ld + (size_t)((c0 ^ (row0 & 7)) * 8);
    const size_t ga1 = ga0 + (size_t)32 * ld;
    const size_t gb0 = (size_t)(bn + row0) * ld + (size_t)((c0 ^ (row0 & 7)) * 8);
    const size_t gb1 = gb0 + (size_t)32 * ld;
    const int lA0 = tid * 16, lA1 = (tid + 256) * 16;
    const int lB0 = 8192 + tid * 16, lB1 = 8192 + (tid + 256) * 16;

    const int lane = tid & 63, wv = tid >> 6;
    const int rA = wv * 16 + (lane & 15);
    const int chnk = (lane >> 4) ^ (lane & 7);
    const int byteA = rA * 128 + chnk * 16;
    const int byteB = 8192 + (lane & 15) * 128 + chnk * 16;

    f32x4 acc[4];
#pragma unroll
    for (int j = 0; j < 4; ++j) acc[j] = (f32x4){0.f, 0.f, 0.f, 0.f};

    auto STAGE = [&](int buf, int kt) {
        const int kw = kt * 64;
        const int ka = (kw >= SEC) ? (kw - SEC) : kw;            // A: hi,hi,lo
        const int kb = (kw >= 2 * SEC) ? (kw - 2 * SEC) : kw;    // W: hi,lo,hi
        const __bf16* a = A + ka;
        const __bf16* w = Wt + kb;
        char* l = &lds[buf][0];
        gload16(a + ga0, l + lA0);
        gload16(a + ga1, l + lA1);
        gload16(w + gb0, l + lB0);
        gload16(w + gb1, l + lB1);
    };

    STAGE(0, ktb);
    asm volatile("s_waitcnt vmcnt(0)" ::: "memory");
    __syncthreads();
    int buf = 0;
    for (int kt = ktb; kt < kte; ++kt) {
        if (kt + 1 < kte) STAGE(buf ^ 1, kt + 1);
        const char* base = &lds[buf][0];
        short8 a0 = *(const short8*)(base + byteA);
        short8 a1 = *(const short8*)(base + (byteA ^ 64));
#pragma unroll
        for (int j = 0; j < 4; ++j) {
            short8 b0 = *(const short8*)(base + (byteB + j * 2048));
            short8 b1 = *(const short8*)(base + ((byteB + j * 2048) ^ 64));
            acc[j] = __builtin_amdgcn_mfma_f32_16x16x32_bf16(a0, b0, acc[j], 0, 0, 0);
            acc[j] = __builtin_amdgcn_mfma_f32_16x16x32_bf16(a1, b1, acc[j], 0, 0, 0);
        }
        asm volatile("s_waitcnt vmcnt(0)" ::: "memory");
        __syncthreads();
        buf ^= 1;
    }
    float* Cz = C + (size_t)z * BATCH * GATES;
    const int crow = bm + wv * 16 + (lane >> 4) * 4;
    const int ccol = bn + (lane & 15);
#pragma unroll
    for (int j = 0; j < 4; ++j)
#pragma unroll
        for (int r = 0; r < 4; ++r)
            Cz[(size_t)(crow + r) * GATES + ccol + j * 16] = acc[j][r];
}

// ---------------------------------------------------------------- fused read (v3: 512 thr)
// attn params + filter bank + glimpse; writes split glimpse|h_dec into A_enc.
// Glimpse: 8 row-groups x 64 lanes x float2; LDS partial reduce over groups.
__global__ __launch_bounds__(512, 4) void read_glimpse_fused(const float* __restrict__ x,
                                                             const float* __restrict__ canvas,
                                                             const float* __restrict__ h_dec,
                                                             const float* __restrict__ Wa,
                                                             const float* __restrict__ ba,
                                                             unsigned short* __restrict__ A_enc) {
    const int b = blockIdx.x, t = threadIdx.x;
    __shared__ float par[5];
    __shared__ float fx[12][132], fy[12][132];
    __shared__ float dn[24];                       // 0..11 fx, 12..23 fy
    __shared__ float tm[12][132], te[12][132];
    __shared__ __align__(16) float pbuf[8][12][128];   // 48 KB; also hosts `red`
    float* red = &pbuf[0][0][0];                   // 5*512 floats, pre-glimpse only
    const float* hb = h_dec + (size_t)b * HID;
    // ---- attn params: 5 x dot(h, Wa_row), tree reduce
#pragma unroll
    for (int j = 0; j < 5; ++j) red[j * 512 + t] = hb[t] * Wa[j * HID + t];
    __syncthreads();
    for (int o = 256; o > 0; o >>= 1) {
        if (t < o) {
#pragma unroll
            for (int j = 0; j < 5; ++j) red[j * 512 + t] += red[j * 512 + t + o];
        }
        __syncthreads();
    }
    if (t < 5) par[t] = red[t * 512] + ba[t];
    __syncthreads();
    const float gx = 129.f * (par[0] + 1.f) * 0.5f;
    const float gy = 129.f * (par[1] + 1.f) * 0.5f;
    const float var = expf(par[2]);
    const float strd = 127.f * expf(par[3]) / 11.f;
    const float iv = expf(par[4]);
    // ---- filters: 3072 entries, 6 per thread
#pragma unroll
    for (int rep = 0; rep < 6; ++rep) {
        int e = t + rep * 512;
        int mat = e / 1536;
        int rr = (e - mat * 1536) >> 7;
        int cc = e & 127;
        float ctr = (mat ? gy : gx) + ((float)rr + 0.5f - 6.f) * strd;
        float d = (float)cc - ctr;
        float v = expf(-(d * d) / (2.f * var));
        float (*dst)[132] = mat ? fy : fx;
        dst[rr][cc] = v;
    }
    __syncthreads();
    if (t < 24) {
        const float (*src)[132] = (t < 12) ? fx : fy;
        int rr = (t < 12) ? t : t - 12;
        float s = 0.f;
        for (int k = 0; k < 128; ++k) s += src[rr][k];
        dn[t] = fmaxf(s, 1e-8f);
    }
    __syncthreads();
#pragma unroll
    for (int rep = 0; rep < 6; ++rep) {
        int e = t + rep * 512;
        int mat = e / 1536;
        int rr = (e - mat * 1536) >> 7;
        int cc = e & 127;
        float (*dst)[132] = mat ? fy : fx;
        dst[rr][cc] /= dn[mat * 12 + rr];
    }
    __syncthreads();
    // ---- glimpse: group g = rows [16g,16g+16), lane l = cols {2l, 2l+1}
    const int g = t >> 6, l = t & 63, c2 = l * 2;
    float2 am[12] = {}, ae[12] = {};
    const float* xb = x + (size_t)b * IMG;
    const float* cb = canvas + (size_t)b * IMG;
    for (int hh = g * 16; hh < g * 16 + 16; ++hh) {
        float2 xv = *(const float2*)(xb + hh * 128 + c2);
        float2 cv = *(const float2*)(cb + hh * 128 + c2);
        float2 xe;
        xe.x = xv.x - 1.f / (1.f + expf(-cv.x));
        xe.y = xv.y - 1.f / (1.f + expf(-cv.y));
#pragma unroll
        for (int i = 0; i < 12; ++i) {
            float f = fy[i][hh];
            am[i].x += f * xv.x;
            am[i].y += f * xv.y;
            ae[i].x += f * xe.x;
            ae[i].y += f * xe.y;
        }
    }
#pragma unroll
    for (int i = 0; i < 12; ++i) *(float2*)(&pbuf[g][i][c2]) = am[i];
    __syncthreads();
    for (int it = t; it < 1536; it += 512) {
        int ii = it >> 7, cc = it & 127;
        float s = 0.f;
#pragma unroll
        for (int k = 0; k < 8; ++k) s += pbuf[k][ii][cc];
        tm[ii][cc] = s;
    }
    __syncthreads();
#pragma unroll
    for (int i = 0; i < 12; ++i) *(float2*)(&pbuf[g][i][c2]) = ae[i];
    __syncthreads();
    for (int it = t; it < 1536; it += 512) {
        int ii = it >> 7, cc = it & 127;
        float s = 0.f;
#pragma unroll
        for (int k = 0; k < 8; ++k) s += pbuf[k][ii][cc];
        te[ii][cc] = s;
    }
    __syncthreads();
    // ---- FxT products -> split into A_enc
    unsigned short hi, lo;
    unsigned short* rb = A_enc + (size_t)b * 2 * SEC_E;
    if (t < 288) {
        int ch = (t >= 144) ? 1 : 0;
        int rem = t - ch * 144;
        int ii = rem / 12, jj = rem - ii * 12;
        const float* src = ch ? te[ii] : tm[ii];
        float s = 0.f;
        for (int w2 = 0; w2 < 128; ++w2) s += src[w2] * fx[jj][w2];
        bsplit(iv * s, hi, lo);
        rb[t] = hi;
        rb[SEC_E + t] = lo;
    }
    bsplit(hb[t], hi, lo);
    rb[288 + t] = hi;
    rb[SEC_E + 288 + t] = lo;
    if (t < 32) {       // zero the K pad (ws is re-poisoned each launch)
        rb[1312 + t] = 0;
        rb[SEC_E + 1312 + t] = 0;
    }
}

// ---------------------------------------------------------------- fp32 NT GEMM (samp)
template <int TM, int TN>
__global__ __launch_bounds__(256) void gemm_slab(const float* __restrict__ A0,
                                                 const float* __restrict__ W0,
                                                 const float* __restrict__ bias0, int ld0, int K0,
                                                 const float* __restrict__ A1,
                                                 const float* __restrict__ W1,
                                                 const float* __restrict__ bias1, int ld1, int K1,
                                                 float* __restrict__ C, int M, int N) {
    constexpr int BM = 16 * TM, BN = 16 * TN, BK = 16;
    __shared__ float As[BK][BM + 4];
    __shared__ float Ws[BK][BN + 4];
    const int z = blockIdx.z;
    const float* A = z ? A1 : A0;
    const float* Wm = z ? W1 : W0;
    const float* bs = z ? bias1 : bias0;
    const int ld = z ? ld1 : ld0;
    const int K = z ? K1 : K0;
    const int tid = threadIdx.x;
    const int tx = tid & 15, ty = tid >> 4;
    const int bm = blockIdx.x * BM, bn = blockIdx.y * BN;
    float acc[TM][TN] = {};
    for (int k0 = 0; k0 < K; k0 += BK) {
        __syncthreads();
        for (int i = tid; i < BM * 4; i += 256) {
            int row = i >> 2, c4 = i & 3;
            const float4 v = *(const float4*)(A + (size_t)(bm + row) * ld + k0 + c4 * 4);
            As[c4 * 4 + 0][row] = v.x;
            As[c4 * 4 + 1][row] = v.y;
            As[c4 * 4 + 2][row] = v.z;
            As[c4 * 4 + 3][row] = v.w;
        }
        for (int i = tid; i < BN * 4; i += 256) {
            int row = i >> 2, c4 = i & 3;
            int wr = bn + row;
            float4 v = make_float4(0.f, 0.f, 0.f, 0.f);
            if (wr < N) v = *(const float4*)(Wm + (size_t)wr * ld + k0 + c4 * 4);
            Ws[c4 * 4 + 0][row] = v.x;
            Ws[c4 * 4 + 1][row] = v.y;
            Ws[c4 * 4 + 2][row] = v.z;
            Ws[c4 * 4 + 3][row] = v.w;
        }
        __syncthreads();
#pragma unroll
        for (int c = 0; c < BK; ++c) {
            float a[TM], w[TN];
#pragma unroll
            for (int i = 0; i < TM; ++i) a[i] = As[c][ty * TM + i];
#pragma unroll
            for (int j = 0; j < TN; ++j) w[j] = Ws[c][tx * TN + j];
#pragma unroll
            for (int i = 0; i < TM; ++i)
#pragma unroll
                for (int j = 0; j < TN; ++j) acc[i][j] += a[i] * w[j];
        }
    }
    float* Cz = C + (size_t)z * M * N;
#pragma unroll
    for (int i = 0; i < TM; ++i) {
        const int rr = bm + ty * TM + i;
#pragma unroll
        for (int j = 0; j < TN; ++j) {
            const int cc = bn + tx * TN + j;
            if (cc < N) Cz[(size_t)rr * N + cc] = acc[i][j] + (bs ? bs[cc] : 0.f);
        }
    }
}

// ---------------------------------------------------------------- LSTM pointwise
__global__ __launch_bounds__(256) void lstm_pw(const float* __restrict__ g0,
                                               const float* __restrict__ g1,
                                               const float* __restrict__ bih,
                                               const float* __restrict__ bhh,
                                               float* __restrict__ h, float* __restrict__ c,
                                               unsigned short* __restrict__ split_out,
                                               int soff, int SEC2) {
    int idx = blockIdx.x * 256 + threadIdx.x;  // B*HID
    int b = idx >> 9, u = idx & 511;
    size_t base = (size_t)b * GATES;
    float gi = g0[base + u] + g1[base + u] + bih[u] + bhh[u];
    float gf = g0[base + 512 + u] + g1[base + 512 + u] + bih[512 + u] + bhh[512 + u];
    float gg = g0[base + 1024 + u] + g1[base + 1024 + u] + bih[1024 + u] + bhh[1024 + u];
    float go = g0[base + 1536 + u] + g1[base + 1536 + u] + bih[1536 + u] + bhh[1536 + u];
    float si = 1.f / (1.f + expf(-gi));
    float sf = 1.f / (1.f + expf(-gf));
    float so = 1.f / (1.f + expf(-go));
    float cn = sf * c[idx] + si * tanhf(gg);
    c[idx] = cn;
    float hn = so * tanhf(cn);
    h[idx] = hn;
    unsigned short hi, lo;
    bsplit(hn, hi, lo);
    size_t sb = (size_t)b * 2 * SEC2;
    split_out[sb + soff + u] = hi;
    split_out[sb + SEC2 + soff + u] = lo;
}

// ---------------------------------------------------------------- z = mu + exp(lv/2)*eps
__global__ __launch_bounds__(256) void z_kernel(const float* __restrict__ s,
                                                const float* __restrict__ eps_t,
                                                unsigned short* __restrict__ A_dec,
                                                float* __restrict__ mu_out,
                                                float* __restrict__ lv_out, int t) {
    int idx = blockIdx.x * 256 + threadIdx.x;  // B*L
    int b = idx >> 7, l = idx & 127;
    int i0 = b * 256 + l;
    float mu = s[i0] + s[131072 + i0];
    float lv = s[i0 + 128] + s[131072 + i0 + 128];
    float zv = mu + expf(0.5f * lv) * eps_t[idx];
    unsigned short hi, lo;
    bsplit(zv, hi, lo);
    size_t bd = (size_t)b * 2 * SEC_D;
    A_dec[bd + l] = hi;
    A_dec[bd + SEC_D + l] = lo;
    size_t o = (size_t)b * (TSTEPS * LAT) + t * LAT + l;
    mu_out[o] = mu;
    lv_out[o] = lv;
}

// ---------------------------------------------------------------- fused write (v3: 512 thr)
// writer GEMM (in-block) + attn params + filter bank + canvas += FyT@w@Fx / inten
__global__ __launch_bounds__(512, 4) void write_canvas_fused(float* __restrict__ canvas,
                                                             const float* __restrict__ h_dec,
                                                             const float* __restrict__ Wr,
                                                             const float* __restrict__ bwr,
                                                             const float* __restrict__ Wa,
                                                             const float* __restrict__ ba) {
    const int b = blockIdx.x, t = threadIdx.x;
    __shared__ float par[5];
    __shared__ float hl[512];
    __shared__ float red[5][512];
    __shared__ float fx[12][132], fyl[12][132];
    __shared__ float dn[24];
    __shared__ float wl[144];
    __shared__ float tl[128][13];
    const float* hb = h_dec + (size_t)b * HID;
    hl[t] = hb[t];
    __syncthreads();
    // ---- attn params
#pragma unroll
    for (int j = 0; j < 5; ++j) red[j][t] = hl[t] * Wa[j * HID + t];
    __syncthreads();
    for (int o = 256; o > 0; o >>= 1) {
        if (t < o) {
#pragma unroll
            for (int j = 0; j < 5; ++j) red[j][t] += red[j][t + o];
        }
        __syncthreads();
    }
    if (t < 5) par[t] = red[t][0] + ba[t];
    __syncthreads();
    const float gx = 129.f * (par[0] + 1.f) * 0.5f;
    const float gy = 129.f * (par[1] + 1.f) * 0.5f;
    const float var = expf(par[2]);
    const float strd = 127.f * expf(par[3]) / 11.f;
    const float riv = 1.f / expf(par[4]);
    // ---- filters (3072 entries, 6/thread)
#pragma unroll
    for (int rep = 0; rep < 6; ++rep) {
        int e = t + rep * 512;
        int mat = e / 1536;
        int rr = (e - mat * 1536) >> 7;
        int cc = e & 127;
        float ctr = (mat ? gy : gx) + ((float)rr + 0.5f - 6.f) * strd;
        float d = (float)cc - ctr;
        float v = expf(-(d * d) / (2.f * var));
        float (*dst)[132] = mat ? fyl : fx;
        dst[rr][cc] = v;
    }
    // ---- writer GEMM: wave wv computes outs [18*wv, 18*wv+18), K=512
    {
        const int wv = t >> 6, l = t & 63;
#pragma unroll
        for (int oi = 0; oi < 18; ++oi) {
            int o = wv * 18 + oi;
            float p = 0.f;
#pragma unroll
            for (int j = 0; j < 8; ++j) p += hl[l + 64 * j] * Wr[(size_t)o * 512 + l + 64 * j];
#pragma unroll
            for (int m = 32; m; m >>= 1) p += __shfl_xor(p, m, 64);
            if (l == 0) wl[o] = p + bwr[o];
        }
    }
    __syncthreads();
    if (t < 24) {
        const float (*src)[132] = (t < 12) ? fx : fyl;
        int rr = (t < 12) ? t : t - 12;
        float s = 0.f;
        for (int k = 0; k < 128; ++k) s += src[rr][k];
        dn[t] = fmaxf(s, 1e-8f);
    }
    __syncthreads();
#pragma unroll
    for (int rep = 0; rep < 6; ++rep) {
        int e = t + rep * 512;
        int mat = e / 1536;
        int rr = (e - mat * 1536) >> 7;
        int cc = e & 127;
        float (*dst)[132] = mat ? fyl : fx;
        dst[rr][cc] /= dn[mat * 12 + rr];
    }
    __syncthreads();
    // ---- tmp[h][j] = sum_i Fy[i][h] * w[i][j]   (threads 0..127, h = t)
    if (t < 128) {
        float tj[12] = {};
#pragma unroll
        for (int i = 0; i < 12; ++i) {
            float f = fyl[i][t];
#pragma unroll
            for (int j = 0; j < 12; ++j) tj[j] += f * wl[i * 12 + j];
        }
#pragma unroll
        for (int j = 0; j < 12; ++j) tl[t][j] = tj[j];
    }
    __syncthreads();
    // ---- canvas RMW: group g rows [16g,16g+16), lane l cols {2l, 2l+1}
    const int g = t >> 6, l = t & 63, c2 = l * 2;
    float* cb = canvas + (size_t)b * IMG;
    for (int hh = g * 16; hh < g * 16 + 16; ++hh) {
        float sx = 0.f, sy = 0.f;
#pragma unroll
        for (int j = 0; j < 12; ++j) {
            float tv = tl[hh][j];
            sx += tv * fx[j][c2];
            sy += tv * fx[j][c2 + 1];
        }
        float2 cv = *(float2*)(cb + hh * 128 + c2);
        cv.x += sx * riv;
        cv.y += sy * riv;
        *(float2*)(cb + hh * 128 + c2) = cv;
    }
}

// ================================================================ host
extern "C" void kernel_launch(void* const* d_in, const int* in_sizes, int n_in,
                              void* d_out, int out_size, void* d_ws, size_t ws_size,
                              hipStream_t stream) {
    const float* x = (const float*)d_in[0];
    const float* eps = (const float*)d_in[1];
    const float* canvas_init = (const float*)d_in[3];
    const float* h_dec_init = (const float*)d_in[4];
    const float* h_enc_init = (const float*)d_in[5];
    const float* W_ih_enc = (const float*)d_in[6];
    const float* b_ih_enc = (const float*)d_in[7];
    const float* W_hh_enc = (const float*)d_in[8];
    const float* b_hh_enc = (const float*)d_in[9];
    const float* W_ih_dec = (const float*)d_in[10];
    const float* b_ih_dec = (const float*)d_in[11];
    const float* W_hh_dec = (const float*)d_in[12];
    const float* b_hh_dec = (const float*)d_in[13];
    const float* W_samp = (const float*)d_in[14];
    const float* b_samp = (const float*)d_in[15];
    const float* W_rattn = (const float*)d_in[16];
    const float* b_rattn = (const float*)d_in[17];
    const float* W_wattn = (const float*)d_in[18];
    const float* b_wattn = (const float*)d_in[19];
    const float* W_writer = (const float*)d_in[20];
    const float* b_writer = (const float*)d_in[21];

    float* out = (float*)d_out;
    float* canvas = out;
    float* out_mu = out + (size_t)BATCH * IMG;
    float* out_lv = out_mu + (size_t)BATCH * TSTEPS * LAT;

    float* ws = (float*)d_ws;
    size_t off = 0;
    auto alloc = [&](size_t n) { float* p = ws + off; off += n; return p; };
    float* h_enc = alloc((size_t)BATCH * HID);
    float* c_enc = alloc((size_t)BATCH * HID);
    float* h_dec = alloc((size_t)BATCH * HID);
    float* c_dec = alloc((size_t)BATCH * HID);
    float* gates = alloc((size_t)2 * BATCH * GATES);
    float* sbuf = alloc((size_t)2 * BATCH * 256);
    unsigned short* A_enc = (unsigned short*)alloc((size_t)BATCH * SEC_E);   // B*2*SEC_E shorts
    unsigned short* A_dec = (unsigned short*)alloc((size_t)BATCH * SEC_D);
    unsigned short* Ws_enc = (unsigned short*)alloc((size_t)GATES * SEC_E);  // N*2*SEC_E shorts
    unsigned short* Ws_dec = (unsigned short*)alloc((size_t)GATES * SEC_D);

    init_canvas<<<BATCH * IMG / 256, 256, 0, stream>>>(canvas, canvas_init);
    init_state<<<BATCH * HID / 256, 256, 0, stream>>>(h_enc, c_enc, h_dec, c_dec,
                                                      h_enc_init, h_dec_init, A_enc, A_dec);
    prep_wsplit<<<dim3((SEC_E + 255) / 256, GATES), 256, 0, stream>>>(W_ih_enc, ENC_IN, W_hh_enc, HID, Ws_enc, SEC_E);
    prep_wsplit<<<dim3((SEC_D + 255) / 256, GATES), 256, 0, stream>>>(W_ih_dec, LAT, W_hh_dec, HID, Ws_dec, SEC_D);

    const int ktE = 3 * SEC_E / 64;   // 63
    const int ktD = 3 * SEC_D / 64;   // 30

    for (int t = 0; t < TSTEPS; ++t) {
        read_glimpse_fused<<<BATCH, 512, 0, stream>>>(x, canvas, h_dec, W_rattn, b_rattn, A_enc);
        gemm_bf16x3<<<dim3(BATCH / 64, GATES / 64, 2), 256, 0, stream>>>(
            A_enc, Ws_enc, gates, SEC_E, 0, 32, 32, ktE);
        lstm_pw<<<BATCH * HID / 256, 256, 0, stream>>>(gates, gates + (size_t)BATCH * GATES,
                                                       b_ih_enc, b_hh_enc, h_enc, c_enc,
                                                       A_enc, 800, SEC_E);
        gemm_slab<4, 1><<<dim3(8, 16, 2), 256, 0, stream>>>(
            h_enc, W_samp, b_samp, HID, 256,
            h_enc + 256, W_samp + 256, nullptr, HID, 256, sbuf, BATCH, 256);
        z_kernel<<<BATCH * LAT / 256, 256, 0, stream>>>(sbuf, eps + (size_t)t * BATCH * LAT,
                                                        A_dec, out_mu, out_lv, t);
        gemm_bf16x3<<<dim3(BATCH / 64, GATES / 64, 2), 256, 0, stream>>>(
            A_dec, Ws_dec, gates, SEC_D, 0, 15, 15, ktD);
        lstm_pw<<<BATCH * HID / 256, 256, 0, stream>>>(gates, gates + (size_t)BATCH * GATES,
                                                       b_ih_dec, b_hh_dec, h_dec, c_dec,
                                                       A_dec, 128, SEC_D);
        write_canvas_fused<<<BATCH, 512, 0, stream>>>(canvas, h_dec, W_writer, b_writer,
                                                      W_wattn, b_wattn);
    }
    sigmoid_final<<<BATCH * IMG / 256, 256, 0, stream>>>(canvas);
}